// Round 5
// baseline (4787.634 us; speedup 1.0000x reference)
//
#include <hip/hip_runtime.h>

#define N_NODES 50000
#define N_EDGES 600000
#define N_GRAPHS 64
#define N_TILES (N_EDGES / 16)   // 37500 wave-tiles
#define NPART 196                // ceil(50000/256) scan partials
#define MEGA_GRID 1536           // 6 blocks/CU on 256 CUs — ALL resident (barrier-safe)
#define MEGA_THREADS (MEGA_GRID * 256)

// constants
#define INV_LIN_IN  0.35355339059327373f   // 1/sqrt(8)
#define INV_LIN_OUT 0.25f                  // 1/sqrt(16)
#define C_INV_S3    0.5773502691896258f    // 1/sqrt(3)
#define C_INV_S2    0.7071067811865476f    // 1/sqrt(2)
#define C_NORM_S    0.04419417382415922f   // 1/sqrt(512)
#define C_NORM_V    0.036084391824351615f  // 1/sqrt(768)

// fp16 overflow guard: features entering layers 1,2 are scaled by ALPHA after
// the gate; the inverse (1/ALPHA^2 = 1024) is folded into those layers' weights.
#define ALPHA      0.03125f                // 1/32
#define W_UNSCALE  1024.0f                 // 1/ALPHA^2

typedef __attribute__((ext_vector_type(8))) _Float16 h16x8;
typedef __attribute__((ext_vector_type(4))) _Float16 h16x4;
typedef __attribute__((ext_vector_type(2))) _Float16 h16x2;
typedef __attribute__((ext_vector_type(4))) float f32x4;

// grid-barrier counters: one slot per phase boundary, zeroed by init each launch
__device__ int g_bars[16];

// device-scope sense-free barrier (per-phase counter, never reset within launch).
// Release fetch_add publishes this block's writes to the IF coherence point
// (wbl2); acquire load invalidates stale L1/L2 before the next phase reads.
__device__ __forceinline__ void gbar(int idx) {
    __threadfence();
    __syncthreads();
    if (threadIdx.x == 0) {
        __hip_atomic_fetch_add(&g_bars[idx], 1, __ATOMIC_RELEASE, __HIP_MEMORY_SCOPE_AGENT);
        while (__hip_atomic_load(&g_bars[idx], __ATOMIC_ACQUIRE, __HIP_MEMORY_SCOPE_AGENT) < MEGA_GRID)
            __builtin_amdgcn_s_sleep(2);
    }
    __syncthreads();
    __threadfence();
}

// -------------------- fused init: proj (fp16 out) + weight swizzle (fp16) +
// counts/energy/acc/barrier zero. Runs as its own dispatch so MEGA's barrier
// counters and sort scratch are clean before any MEGA block starts.
__global__ void init_kernel(const float* __restrict__ x,
                            const float* __restrict__ w_in0,
                            const float* __restrict__ w_in1,
                            const float* __restrict__ tp_w,
                            h16x4* __restrict__ featH,
                            _Float16* __restrict__ wh,
                            int* __restrict__ counts,
                            float* __restrict__ energy,
                            float4* __restrict__ acc) {
    int gid = blockIdx.x * 256 + threadIdx.x;

    if (gid < 16) g_bars[gid] = 0;
    if (gid < 64) energy[gid] = 0.f;
    if (gid < N_NODES) counts[gid] = 0;

    // zero the f32 accumulator: 800k float4 over 61440 threads (grid-stride)
    for (int idx = gid; idx < N_NODES * 16; idx += 61440)
        acc[idx] = make_float4(0.f, 0.f, 0.f, 0.f);

    if (gid < 3 * 20480) {   // weight swizzle -> fp16 (one-time cost)
        int i = gid;
        int j    = i & 7;
        int t1   = i >> 3;
        int lane = t1 & 63;
        int t2   = t1 >> 6;
        int c    = t2 & 7;
        int t3   = t2 >> 3;
        int slot = t3 % 5;
        int l    = t3 / 5;
        int p = (slot == 0) ? 1 : (slot == 1) ? 2 : (slot == 2) ? 4 : (slot == 3) ? 0 : 3;
        int kk = c * 32 + (lane >> 4) * 8 + j;
        int u = kk >> 4, v = kk & 15, n = lane & 15;
        float scale;
        if      (p == 0) scale = C_NORM_S;
        else if (p == 3) scale = C_INV_S3 * C_NORM_S;
        else if (p == 4) scale = C_INV_S2 * C_NORM_V;
        else             scale = C_NORM_V;   // p==1, p==2
        if (l > 0) scale *= W_UNSCALE;       // undo ALPHA^2 feature pre-scale
        float val = tp_w[(size_t)(l * 5 + p) * 4096 + u * 256 + v * 16 + n] * scale;
        wh[i] = (_Float16)val;
    }

    if (gid < N_NODES) {     // input projection -> fp16 features (layer-0: unscaled)
        const float* xp = x + (size_t)gid * 32;
        float xs[8], xvx[8], xvy[8], xvz[8];
#pragma unroll
        for (int u = 0; u < 8; ++u) xs[u] = xp[u];
#pragma unroll
        for (int u = 0; u < 8; ++u) {
            xvx[u] = xp[8 + 3 * u + 0];
            xvy[u] = xp[8 + 3 * u + 1];
            xvz[u] = xp[8 + 3 * u + 2];
        }
#pragma unroll
        for (int w = 0; w < 16; ++w) {
            float s = 0.f, vx = 0.f, vy = 0.f, vz = 0.f;
#pragma unroll
            for (int u = 0; u < 8; ++u) {
                float a0 = w_in0[u * 16 + w];
                float a1 = w_in1[u * 16 + w];
                s  += xs[u]  * a0;
                vx += xvx[u] * a1;
                vy += xvy[u] * a1;
                vz += xvz[u] * a1;
            }
            h16x4 o;
            o.x = (_Float16)(s  * INV_LIN_IN);
            o.y = (_Float16)(vx * INV_LIN_IN);
            o.z = (_Float16)(vy * INV_LIN_IN);
            o.w = (_Float16)(vz * INV_LIN_IN);
            featH[(size_t)gid * 16 + w] = o;
        }
    }
}

// ==================== MEGA persistent kernel ====================
// Phases: hist | scan_part | scan_final | scatter | 3x(edge [+gate]) | readout
// separated by device-scope grid barriers. Grid = 1536 (6 blocks/CU, all
// resident; launch_bounds(256,6) caps regs at ~84/wave — current edge phase
// uses 60 VGPR + 16 AGPR = 76, no spill).
__global__ __launch_bounds__(256, 6)
void mega_kernel(const int* __restrict__ row, const int* __restrict__ col,
                 const int* __restrict__ batch_idx,
                 const float* __restrict__ w_out,
                 const _Float16* __restrict__ wh,
                 float* __restrict__ acc,
                 _Float16* __restrict__ featA,
                 _Float16* __restrict__ featB,
                 int* __restrict__ sortedRC,
                 float* __restrict__ energy) {
    __shared__ __align__(16) char smraw[16384];

    const int t   = threadIdx.x;
    const int tid = blockIdx.x * 256 + t;

    // sort scratch aliased into featB (dead until gate0 writes featB at bar 5)
    int* counts  = (int*)featB;
    int* cursor  = counts + N_NODES;
    int* partial = cursor + N_NODES;

    // ---------- P0: histogram ----------
    for (int e = tid; e < N_EDGES; e += MEGA_THREADS)
        atomicAdd(&counts[row[e]], 1);
    gbar(0);

    // ---------- P1: per-256-chunk sums ----------
    if (blockIdx.x < NPART) {
        int* sm = (int*)smraw;
        int i = blockIdx.x * 256 + t;
        sm[t] = (i < N_NODES) ? counts[i] : 0;
        __syncthreads();
        for (int s = 128; s > 0; s >>= 1) {
            if (t < s) sm[t] += sm[t + s];
            __syncthreads();
        }
        if (t == 0) partial[blockIdx.x] = sm[0];
    }
    gbar(1);

    // ---------- P2: final exclusive scan ----------
    if (blockIdx.x < NPART) {
        int* sm  = (int*)smraw;
        int* sm2 = sm + 256;
        int i = blockIdx.x * 256 + t;
        int v = (i < N_NODES) ? counts[i] : 0;
        sm[t] = v;
        sm2[t] = (t < NPART && t < blockIdx.x) ? partial[t] : 0;
        __syncthreads();
        for (int s = 128; s > 0; s >>= 1) {
            if (t < s) sm2[t] += sm2[t + s];
            __syncthreads();
        }
        int base = sm2[0];
        for (int s = 1; s < 256; s <<= 1) {
            int add = (t >= s) ? sm[t - s] : 0;
            __syncthreads();
            sm[t] += add;
            __syncthreads();
        }
        if (i < N_NODES) cursor[i] = sm[t] - v + base;
    }
    gbar(2);

    // ---------- P3: scatter into destination-sorted order ----------
    for (int e = tid; e < N_EDGES; e += MEGA_THREADS) {
        int n = row[e];
        int pos = atomicAdd(&cursor[n], 1);
        sortedRC[pos] = n | (col[e] << 16);   // node ids < 50000 < 65536
    }
    gbar(3);

    // ---------- layers ----------
    const int lane = t & 63;
    const int wave = t >> 6;
    const int q = lane >> 4;        // quad 0..3
    const int m = lane & 15;        // edge-in-tile / w column
    const int v0 = (q & 1) * 8;
    const int gw_id = blockIdx.x * 4 + wave;
    const int nw = MEGA_GRID * 4;
    const int tile0   = (int)(((long long)gw_id * N_TILES) / nw);
    const int tileEnd = (int)(((long long)(gw_id + 1) * N_TILES) / nw);

    const _Float16* finp = featA;
    _Float16* foutp = featB;
    int barIdx = 4;

    for (int l = 0; l < 3; ++l) {
        // refill LDS with this layer's paths {1,2}
        const _Float16* whl = wh + (size_t)l * 20480;
        {
            const int4* src = (const int4*)whl;
            int4* dst = (int4*)smraw;
#pragma unroll
            for (int i = 0; i < 4; ++i) dst[t + 256 * i] = src[t + 256 * i];
        }
        __syncthreads();
        const h16x8* sW = (const h16x8*)smraw;
        const h16x8* gw = ((const h16x8*)whl) + 1024;   // paths {4,0,3} in global
        const h16x4* feat = (const h16x4*)finp;

        // -------- edge tensor-product phase (identical to R4's proven loop) ----
        if (tile0 < tileEnd) {
            int tile = tile0;
            int rc = sortedRC[tile * 16 + m];
            h16x4 Bt[8];
            {
                const h16x4* bp = feat + (size_t)(((unsigned)rc) >> 16) * 16 + v0;
#pragma unroll
                for (int k = 0; k < 8; ++k) Bt[k] = bp[k];
            }

            for (; tile < tileEnd; ++tile) {
                const int myR = rc & 0xFFFF;
                const int nt = tile + 1;
                const int nrc = (nt < tileEnd) ? sortedRC[nt * 16 + m] : rc;

                h16x2 Bs[4], Bx[4], By[4], Bz[4];
#pragma unroll
                for (int k = 0; k < 4; ++k) {
                    Bs[k].x = Bt[2 * k].x; Bs[k].y = Bt[2 * k + 1].x;
                    Bx[k].x = Bt[2 * k].y; Bx[k].y = Bt[2 * k + 1].y;
                    By[k].x = Bt[2 * k].z; By[k].y = Bt[2 * k + 1].z;
                    Bz[k].x = Bt[2 * k].w; Bz[k].y = Bt[2 * k + 1].w;
                }

                f32x4 acc_s = {0.f, 0.f, 0.f, 0.f};
                f32x4 acc_x = {0.f, 0.f, 0.f, 0.f};
                f32x4 acc_y = {0.f, 0.f, 0.f, 0.f};
                f32x4 acc_z = {0.f, 0.f, 0.f, 0.f};

                const h16x4* ap = feat + (size_t)myR * 16;

#pragma unroll 4
                for (int c = 0; c < 8; ++c) {
                    h16x8 w4f = gw[(0 * 8 + c) * 64 + lane];   // path 4 (cross)
                    h16x8 w0f = gw[(1 * 8 + c) * 64 + lane];   // path 0 (ss)
                    h16x8 w3f = gw[(2 * 8 + c) * 64 + lane];   // path 3 (dot)
                    h16x8 w1f = sW[(0 * 8 + c) * 64 + lane];
                    h16x8 w2f = sW[(1 * 8 + c) * 64 + lane];

                    h16x4 A = ap[2 * c + (q >> 1)];   // L1-hot (sorted rows)
                    h16x2 s2; s2.x = A.x; s2.y = A.x;
                    h16x2 x2; x2.x = A.y; x2.y = A.y;
                    h16x2 y2; y2.x = A.z; y2.y = A.z;
                    h16x2 z2; z2.x = A.w; z2.y = A.w;

                    union { h16x8 v; h16x2 h[4]; } z;

#pragma unroll
                    for (int k = 0; k < 4; ++k) z.h[k] = s2 * Bs[k];
                    acc_s = __builtin_amdgcn_mfma_f32_16x16x32_f16(z.v, w0f, acc_s, 0, 0, 0);

#pragma unroll
                    for (int k = 0; k < 4; ++k)
                        z.h[k] = x2 * Bx[k] + y2 * By[k] + z2 * Bz[k];
                    acc_s = __builtin_amdgcn_mfma_f32_16x16x32_f16(z.v, w3f, acc_s, 0, 0, 0);

#pragma unroll
                    for (int k = 0; k < 4; ++k) z.h[k] = s2 * Bx[k];
                    acc_x = __builtin_amdgcn_mfma_f32_16x16x32_f16(z.v, w1f, acc_x, 0, 0, 0);
#pragma unroll
                    for (int k = 0; k < 4; ++k) z.h[k] = x2 * Bs[k];
                    acc_x = __builtin_amdgcn_mfma_f32_16x16x32_f16(z.v, w2f, acc_x, 0, 0, 0);
#pragma unroll
                    for (int k = 0; k < 4; ++k) z.h[k] = y2 * Bz[k] - z2 * By[k];
                    acc_x = __builtin_amdgcn_mfma_f32_16x16x32_f16(z.v, w4f, acc_x, 0, 0, 0);

#pragma unroll
                    for (int k = 0; k < 4; ++k) z.h[k] = s2 * By[k];
                    acc_y = __builtin_amdgcn_mfma_f32_16x16x32_f16(z.v, w1f, acc_y, 0, 0, 0);
#pragma unroll
                    for (int k = 0; k < 4; ++k) z.h[k] = y2 * Bs[k];
                    acc_y = __builtin_amdgcn_mfma_f32_16x16x32_f16(z.v, w2f, acc_y, 0, 0, 0);
#pragma unroll
                    for (int k = 0; k < 4; ++k) z.h[k] = z2 * Bx[k] - x2 * Bz[k];
                    acc_y = __builtin_amdgcn_mfma_f32_16x16x32_f16(z.v, w4f, acc_y, 0, 0, 0);

#pragma unroll
                    for (int k = 0; k < 4; ++k) z.h[k] = s2 * Bz[k];
                    acc_z = __builtin_amdgcn_mfma_f32_16x16x32_f16(z.v, w1f, acc_z, 0, 0, 0);
#pragma unroll
                    for (int k = 0; k < 4; ++k) z.h[k] = z2 * Bs[k];
                    acc_z = __builtin_amdgcn_mfma_f32_16x16x32_f16(z.v, w2f, acc_z, 0, 0, 0);
#pragma unroll
                    for (int k = 0; k < 4; ++k) z.h[k] = x2 * By[k] - y2 * Bx[k];
                    acc_z = __builtin_amdgcn_mfma_f32_16x16x32_f16(z.v, w4f, acc_z, 0, 0, 0);
                }

                // prefetch next tile's B
                {
                    const h16x4* nbp = feat + (size_t)(((unsigned)nrc) >> 16) * 16 + v0;
#pragma unroll
                    for (int k = 0; k < 8; ++k) Bt[k] = nbp[k];
                }

                // wave-local segmented epilogue
                int prevR = __shfl(myR, (lane + 63) & 63);
                int flag = (m == 0) || (myR != prevR);
                unsigned long long bal = __ballot(flag != 0);
                unsigned mask16 = (unsigned)(bal & 0xFFFFull);

                int nseg = __popc(mask16);
                unsigned rem = mask16;
                for (int s = 0; s < nseg; ++s) {
                    int lo = __ffs(rem) - 1;
                    rem &= rem - 1;
                    int hi = rem ? (__ffs(rem) - 1) : 16;
                    float ps = 0.f, px = 0.f, py = 0.f, pz = 0.f;
#pragma unroll
                    for (int r = 0; r < 4; ++r) {
                        int ei = q * 4 + r;
                        bool in = (ei >= lo) && (ei < hi);
                        ps += in ? acc_s[r] : 0.f;
                        px += in ? acc_x[r] : 0.f;
                        py += in ? acc_y[r] : 0.f;
                        pz += in ? acc_z[r] : 0.f;
                    }
                    ps += __shfl_xor(ps, 16); ps += __shfl_xor(ps, 32);
                    px += __shfl_xor(px, 16); px += __shfl_xor(px, 32);
                    py += __shfl_xor(py, 16); py += __shfl_xor(py, 32);
                    pz += __shfl_xor(pz, 16); pz += __shfl_xor(pz, 32);
                    int node = __shfl(myR, lo);
                    float val = (q == 0) ? ps : (q == 1) ? px : (q == 2) ? py : pz;
                    atomicAdd(acc + (size_t)node * 64 + m * 4 + q, val);
                }

                rc = nrc;
            }
        }
        gbar(barIdx++);   // edge phase l complete

        if (l < 2) {
            // -------- gate phase: acc -> fp16 (xALPHA), rezero acc --------
            float4* accv = (float4*)acc;
            h16x4* fo = (h16x4*)foutp;
            for (int i = tid; i < N_NODES * 16; i += MEGA_THREADS) {
                float4 f = accv[i];
                float g = ALPHA / (1.f + __expf(-f.x));
                h16x4 o;
                o.x = (_Float16)(f.x * g);
                o.y = (_Float16)(f.y * g);
                o.z = (_Float16)(f.z * g);
                o.w = (_Float16)(f.w * g);
                fo[i] = o;
                accv[i] = make_float4(0.f, 0.f, 0.f, 0.f);
            }
            // ping-pong
            const _Float16* tmp = finp; finp = foutp; foutp = (_Float16*)tmp;
            gbar(barIdx++);   // gate l complete
        } else {
            // -------- readout phase --------
            float* bins = (float*)smraw;   // edge phase done; LDS reusable
            if (t < N_GRAPHS) bins[t] = 0.f;
            __syncthreads();
            for (int n = tid; n < N_NODES; n += MEGA_THREADS) {
                const float4* f = (const float4*)acc + (size_t)n * 16;
                float a = 0.f;
#pragma unroll
                for (int w = 0; w < 16; ++w) {
                    float s = f[w].x;
                    float silu = s / (1.f + __expf(-s));
                    a += silu * w_out[w];
                }
                atomicAdd(&bins[batch_idx[n]], a * INV_LIN_OUT);
            }
            __syncthreads();
            if (t < N_GRAPHS) atomicAdd(&energy[t], bins[t]);
        }
    }
}

extern "C" void kernel_launch(void* const* d_in, const int* in_sizes, int n_in,
                              void* d_out, int out_size, void* d_ws, size_t ws_size,
                              hipStream_t stream) {
    const float* x         = (const float*)d_in[0];
    const int*   row       = (const int*)d_in[1];
    const int*   col       = (const int*)d_in[2];
    const int*   batch_idx = (const int*)d_in[3];
    const float* w_in0     = (const float*)d_in[4];
    const float* w_in1     = (const float*)d_in[5];
    const float* tp_w      = (const float*)d_in[6];   // [3][5][16][16][16]
    const float* w_out0    = (const float*)d_in[7];
    float* energy = (float*)d_out;

    // workspace layout (28.1 MB total)
    float*    acc   = (float*)d_ws;                        // [N][64] f32 accum
    _Float16* featA = (_Float16*)(acc + (size_t)N_NODES * 64);   // [N][64] f16
    _Float16* featB = featA + (size_t)N_NODES * 64;              // [N][64] f16
    _Float16* wh    = featB + (size_t)N_NODES * 64;              // [3][20480] f16
    int* sortedRC = (int*)(wh + 3 * 20480);                // [E] packed (row | col<<16)
    int* counts  = (int*)featB;   // transient sort scratch (dead until gate0)

    // dispatch 1: proj -> featA (fp16), swizzle -> wh, zero counts/energy/acc/bars
    init_kernel<<<(3 * 20480 + 255) / 256, 256, 0, stream>>>(
        x, w_in0, w_in1, tp_w, (h16x4*)featA, wh, counts, energy, (float4*)acc);

    // dispatch 2: everything else, grid-barrier separated
    mega_kernel<<<MEGA_GRID, 256, 0, stream>>>(
        row, col, batch_idx, w_out0, wh, acc, featA, featB, sortedRC, energy);
}

// Round 6
// 2977.408 us; speedup vs baseline: 1.6080x; 1.6080x over previous
//
#include <hip/hip_runtime.h>

#define N_NODES 50000
#define N_EDGES 600000
#define N_GRAPHS 64
#define N_TILES (N_EDGES / 16)   // 37500 wave-tiles
#define NPART 196                // ceil(50000/256) scan partials
#define MEGA_GRID 1024           // 4 blocks/CU on 256 CUs — ALL resident (barrier-safe)
#define MEGA_THREADS (MEGA_GRID * 256)

// constants
#define INV_LIN_IN  0.35355339059327373f   // 1/sqrt(8)
#define INV_LIN_OUT 0.25f                  // 1/sqrt(16)
#define C_INV_S3    0.5773502691896258f    // 1/sqrt(3)
#define C_INV_S2    0.7071067811865476f    // 1/sqrt(2)
#define C_NORM_S    0.04419417382415922f   // 1/sqrt(512)
#define C_NORM_V    0.036084391824351615f  // 1/sqrt(768)

// fp16 overflow guard: features entering layers 1,2 are scaled by ALPHA after
// the gate; the inverse (1/ALPHA^2 = 1024) is folded into those layers' weights.
#define ALPHA      0.03125f                // 1/32
#define W_UNSCALE  1024.0f                 // 1/ALPHA^2

typedef __attribute__((ext_vector_type(8))) _Float16 h16x8;
typedef __attribute__((ext_vector_type(4))) _Float16 h16x4;
typedef __attribute__((ext_vector_type(2))) _Float16 h16x2;
typedef __attribute__((ext_vector_type(4))) float f32x4;

// grid-barrier counters: one slot per phase boundary, zeroed by init each launch
__device__ int g_bars[16];

// device-scope sense-free barrier (per-phase counter, never reset within launch).
// Release fetch_add publishes this block's writes; acquire load invalidates
// stale caches before the next phase reads. Proven correct in R5.
__device__ __forceinline__ void gbar(int idx) {
    __threadfence();
    __syncthreads();
    if (threadIdx.x == 0) {
        __hip_atomic_fetch_add(&g_bars[idx], 1, __ATOMIC_RELEASE, __HIP_MEMORY_SCOPE_AGENT);
        while (__hip_atomic_load(&g_bars[idx], __ATOMIC_ACQUIRE, __HIP_MEMORY_SCOPE_AGENT) < MEGA_GRID)
            __builtin_amdgcn_s_sleep(2);
    }
    __syncthreads();
    __threadfence();
}

// -------------------- fused init: proj (fp16 out) + weight swizzle (fp16) +
// counts/energy/acc/barrier zero.
__global__ void init_kernel(const float* __restrict__ x,
                            const float* __restrict__ w_in0,
                            const float* __restrict__ w_in1,
                            const float* __restrict__ tp_w,
                            h16x4* __restrict__ featH,
                            _Float16* __restrict__ wh,
                            int* __restrict__ counts,
                            float* __restrict__ energy,
                            float4* __restrict__ acc) {
    int gid = blockIdx.x * 256 + threadIdx.x;

    if (gid < 16) g_bars[gid] = 0;
    if (gid < 64) energy[gid] = 0.f;
    if (gid < N_NODES) counts[gid] = 0;

    // zero the f32 accumulator: 800k float4 over 61440 threads (grid-stride)
    for (int idx = gid; idx < N_NODES * 16; idx += 61440)
        acc[idx] = make_float4(0.f, 0.f, 0.f, 0.f);

    if (gid < 3 * 20480) {   // weight swizzle -> fp16 (one-time cost)
        int i = gid;
        int j    = i & 7;
        int t1   = i >> 3;
        int lane = t1 & 63;
        int t2   = t1 >> 6;
        int c    = t2 & 7;
        int t3   = t2 >> 3;
        int slot = t3 % 5;
        int l    = t3 / 5;
        int p = (slot == 0) ? 1 : (slot == 1) ? 2 : (slot == 2) ? 4 : (slot == 3) ? 0 : 3;
        int kk = c * 32 + (lane >> 4) * 8 + j;
        int u = kk >> 4, v = kk & 15, n = lane & 15;
        float scale;
        if      (p == 0) scale = C_NORM_S;
        else if (p == 3) scale = C_INV_S3 * C_NORM_S;
        else if (p == 4) scale = C_INV_S2 * C_NORM_V;
        else             scale = C_NORM_V;   // p==1, p==2
        if (l > 0) scale *= W_UNSCALE;       // undo ALPHA^2 feature pre-scale
        float val = tp_w[(size_t)(l * 5 + p) * 4096 + u * 256 + v * 16 + n] * scale;
        wh[i] = (_Float16)val;
    }

    if (gid < N_NODES) {     // input projection -> fp16 features (layer-0: unscaled)
        const float* xp = x + (size_t)gid * 32;
        float xs[8], xvx[8], xvy[8], xvz[8];
#pragma unroll
        for (int u = 0; u < 8; ++u) xs[u] = xp[u];
#pragma unroll
        for (int u = 0; u < 8; ++u) {
            xvx[u] = xp[8 + 3 * u + 0];
            xvy[u] = xp[8 + 3 * u + 1];
            xvz[u] = xp[8 + 3 * u + 2];
        }
#pragma unroll
        for (int w = 0; w < 16; ++w) {
            float s = 0.f, vx = 0.f, vy = 0.f, vz = 0.f;
#pragma unroll
            for (int u = 0; u < 8; ++u) {
                float a0 = w_in0[u * 16 + w];
                float a1 = w_in1[u * 16 + w];
                s  += xs[u]  * a0;
                vx += xvx[u] * a1;
                vy += xvy[u] * a1;
                vz += xvz[u] * a1;
            }
            h16x4 o;
            o.x = (_Float16)(s  * INV_LIN_IN);
            o.y = (_Float16)(vx * INV_LIN_IN);
            o.z = (_Float16)(vy * INV_LIN_IN);
            o.w = (_Float16)(vz * INV_LIN_IN);
            featH[(size_t)gid * 16 + w] = o;
        }
    }
}

// ==================== MEGA persistent kernel ====================
// Phases: hist | scan_part | scan_final | scatter | 3x(edge [+gate]) | readout
// separated by device-scope grid barriers (R5-proven). Grid = 1024 (4 blocks/CU,
// all resident). launch_bounds(256,4) -> reg cap 128: the R4 edge loop compiled
// to 60 VGPR under this exact bound, so NO spills (R5's (256,6) cap-84 spilled
// the MFMA loop to scratch -> 1.2 GB/dispatch of spill traffic -> 10x slowdown).
__global__ __launch_bounds__(256, 4)
void mega_kernel(const int* __restrict__ row, const int* __restrict__ col,
                 const int* __restrict__ batch_idx,
                 const float* __restrict__ w_out,
                 const _Float16* __restrict__ wh,
                 float* __restrict__ acc,
                 _Float16* __restrict__ featA,
                 _Float16* __restrict__ featB,
                 int* __restrict__ sortedRC,
                 float* __restrict__ energy) {
    __shared__ __align__(16) char smraw[16384];

    const int t   = threadIdx.x;
    const int tid = blockIdx.x * 256 + t;

    // sort scratch aliased into featB (dead until gate0 writes featB at bar 5)
    int* counts  = (int*)featB;
    int* cursor  = counts + N_NODES;
    int* partial = cursor + N_NODES;

    // ---------- P0: histogram ----------
    for (int e = tid; e < N_EDGES; e += MEGA_THREADS)
        atomicAdd(&counts[row[e]], 1);
    gbar(0);

    // ---------- P1: per-256-chunk sums ----------
    if (blockIdx.x < NPART) {
        int* sm = (int*)smraw;
        int i = blockIdx.x * 256 + t;
        sm[t] = (i < N_NODES) ? counts[i] : 0;
        __syncthreads();
        for (int s = 128; s > 0; s >>= 1) {
            if (t < s) sm[t] += sm[t + s];
            __syncthreads();
        }
        if (t == 0) partial[blockIdx.x] = sm[0];
    }
    gbar(1);

    // ---------- P2: final exclusive scan ----------
    if (blockIdx.x < NPART) {
        int* sm  = (int*)smraw;
        int* sm2 = sm + 256;
        int i = blockIdx.x * 256 + t;
        int v = (i < N_NODES) ? counts[i] : 0;
        sm[t] = v;
        sm2[t] = (t < NPART && t < blockIdx.x) ? partial[t] : 0;
        __syncthreads();
        for (int s = 128; s > 0; s >>= 1) {
            if (t < s) sm2[t] += sm2[t + s];
            __syncthreads();
        }
        int base = sm2[0];
        for (int s = 1; s < 256; s <<= 1) {
            int add = (t >= s) ? sm[t - s] : 0;
            __syncthreads();
            sm[t] += add;
            __syncthreads();
        }
        if (i < N_NODES) cursor[i] = sm[t] - v + base;
    }
    gbar(2);

    // ---------- P3: scatter into destination-sorted order ----------
    for (int e = tid; e < N_EDGES; e += MEGA_THREADS) {
        int n = row[e];
        int pos = atomicAdd(&cursor[n], 1);
        sortedRC[pos] = n | (col[e] << 16);   // node ids < 50000 < 65536
    }
    gbar(3);

    // ---------- layers ----------
    const int lane = t & 63;
    const int wave = t >> 6;
    const int q = lane >> 4;        // quad 0..3
    const int m = lane & 15;        // edge-in-tile / w column
    const int v0 = (q & 1) * 8;
    const int gw_id = blockIdx.x * 4 + wave;
    const int nw = MEGA_GRID * 4;
    const int tile0   = (int)(((long long)gw_id * N_TILES) / nw);
    const int tileEnd = (int)(((long long)(gw_id + 1) * N_TILES) / nw);

    const _Float16* finp = featA;
    _Float16* foutp = featB;
    int barIdx = 4;

    for (int l = 0; l < 3; ++l) {
        // refill LDS with this layer's paths {1,2}
        const _Float16* whl = wh + (size_t)l * 20480;
        {
            const int4* src = (const int4*)whl;
            int4* dst = (int4*)smraw;
#pragma unroll
            for (int i = 0; i < 4; ++i) dst[t + 256 * i] = src[t + 256 * i];
        }
        __syncthreads();
        const h16x8* sW = (const h16x8*)smraw;
        const h16x8* gw = ((const h16x8*)whl) + 1024;   // paths {4,0,3} in global
        const h16x4* feat = (const h16x4*)finp;

        // -------- edge tensor-product phase (identical to R4's proven loop) ----
        if (tile0 < tileEnd) {
            int tile = tile0;
            int rc = sortedRC[tile * 16 + m];
            h16x4 Bt[8];
            {
                const h16x4* bp = feat + (size_t)(((unsigned)rc) >> 16) * 16 + v0;
#pragma unroll
                for (int k = 0; k < 8; ++k) Bt[k] = bp[k];
            }

            for (; tile < tileEnd; ++tile) {
                const int myR = rc & 0xFFFF;
                const int nt = tile + 1;
                const int nrc = (nt < tileEnd) ? sortedRC[nt * 16 + m] : rc;

                h16x2 Bs[4], Bx[4], By[4], Bz[4];
#pragma unroll
                for (int k = 0; k < 4; ++k) {
                    Bs[k].x = Bt[2 * k].x; Bs[k].y = Bt[2 * k + 1].x;
                    Bx[k].x = Bt[2 * k].y; Bx[k].y = Bt[2 * k + 1].y;
                    By[k].x = Bt[2 * k].z; By[k].y = Bt[2 * k + 1].z;
                    Bz[k].x = Bt[2 * k].w; Bz[k].y = Bt[2 * k + 1].w;
                }

                f32x4 acc_s = {0.f, 0.f, 0.f, 0.f};
                f32x4 acc_x = {0.f, 0.f, 0.f, 0.f};
                f32x4 acc_y = {0.f, 0.f, 0.f, 0.f};
                f32x4 acc_z = {0.f, 0.f, 0.f, 0.f};

                const h16x4* ap = feat + (size_t)myR * 16;

#pragma unroll 4
                for (int c = 0; c < 8; ++c) {
                    h16x8 w4f = gw[(0 * 8 + c) * 64 + lane];   // path 4 (cross)
                    h16x8 w0f = gw[(1 * 8 + c) * 64 + lane];   // path 0 (ss)
                    h16x8 w3f = gw[(2 * 8 + c) * 64 + lane];   // path 3 (dot)
                    h16x8 w1f = sW[(0 * 8 + c) * 64 + lane];
                    h16x8 w2f = sW[(1 * 8 + c) * 64 + lane];

                    h16x4 A = ap[2 * c + (q >> 1)];   // L1-hot (sorted rows)
                    h16x2 s2; s2.x = A.x; s2.y = A.x;
                    h16x2 x2; x2.x = A.y; x2.y = A.y;
                    h16x2 y2; y2.x = A.z; y2.y = A.z;
                    h16x2 z2; z2.x = A.w; z2.y = A.w;

                    union { h16x8 v; h16x2 h[4]; } z;

#pragma unroll
                    for (int k = 0; k < 4; ++k) z.h[k] = s2 * Bs[k];
                    acc_s = __builtin_amdgcn_mfma_f32_16x16x32_f16(z.v, w0f, acc_s, 0, 0, 0);

#pragma unroll
                    for (int k = 0; k < 4; ++k)
                        z.h[k] = x2 * Bx[k] + y2 * By[k] + z2 * Bz[k];
                    acc_s = __builtin_amdgcn_mfma_f32_16x16x32_f16(z.v, w3f, acc_s, 0, 0, 0);

#pragma unroll
                    for (int k = 0; k < 4; ++k) z.h[k] = s2 * Bx[k];
                    acc_x = __builtin_amdgcn_mfma_f32_16x16x32_f16(z.v, w1f, acc_x, 0, 0, 0);
#pragma unroll
                    for (int k = 0; k < 4; ++k) z.h[k] = x2 * Bs[k];
                    acc_x = __builtin_amdgcn_mfma_f32_16x16x32_f16(z.v, w2f, acc_x, 0, 0, 0);
#pragma unroll
                    for (int k = 0; k < 4; ++k) z.h[k] = y2 * Bz[k] - z2 * By[k];
                    acc_x = __builtin_amdgcn_mfma_f32_16x16x32_f16(z.v, w4f, acc_x, 0, 0, 0);

#pragma unroll
                    for (int k = 0; k < 4; ++k) z.h[k] = s2 * By[k];
                    acc_y = __builtin_amdgcn_mfma_f32_16x16x32_f16(z.v, w1f, acc_y, 0, 0, 0);
#pragma unroll
                    for (int k = 0; k < 4; ++k) z.h[k] = y2 * Bs[k];
                    acc_y = __builtin_amdgcn_mfma_f32_16x16x32_f16(z.v, w2f, acc_y, 0, 0, 0);
#pragma unroll
                    for (int k = 0; k < 4; ++k) z.h[k] = z2 * Bx[k] - x2 * Bz[k];
                    acc_y = __builtin_amdgcn_mfma_f32_16x16x32_f16(z.v, w4f, acc_y, 0, 0, 0);

#pragma unroll
                    for (int k = 0; k < 4; ++k) z.h[k] = s2 * Bz[k];
                    acc_z = __builtin_amdgcn_mfma_f32_16x16x32_f16(z.v, w1f, acc_z, 0, 0, 0);
#pragma unroll
                    for (int k = 0; k < 4; ++k) z.h[k] = z2 * Bs[k];
                    acc_z = __builtin_amdgcn_mfma_f32_16x16x32_f16(z.v, w2f, acc_z, 0, 0, 0);
#pragma unroll
                    for (int k = 0; k < 4; ++k) z.h[k] = x2 * By[k] - y2 * Bx[k];
                    acc_z = __builtin_amdgcn_mfma_f32_16x16x32_f16(z.v, w4f, acc_z, 0, 0, 0);
                }

                // prefetch next tile's B
                {
                    const h16x4* nbp = feat + (size_t)(((unsigned)nrc) >> 16) * 16 + v0;
#pragma unroll
                    for (int k = 0; k < 8; ++k) Bt[k] = nbp[k];
                }

                // wave-local segmented epilogue
                int prevR = __shfl(myR, (lane + 63) & 63);
                int flag = (m == 0) || (myR != prevR);
                unsigned long long bal = __ballot(flag != 0);
                unsigned mask16 = (unsigned)(bal & 0xFFFFull);

                int nseg = __popc(mask16);
                unsigned rem = mask16;
                for (int s = 0; s < nseg; ++s) {
                    int lo = __ffs(rem) - 1;
                    rem &= rem - 1;
                    int hi = rem ? (__ffs(rem) - 1) : 16;
                    float ps = 0.f, px = 0.f, py = 0.f, pz = 0.f;
#pragma unroll
                    for (int r = 0; r < 4; ++r) {
                        int ei = q * 4 + r;
                        bool in = (ei >= lo) && (ei < hi);
                        ps += in ? acc_s[r] : 0.f;
                        px += in ? acc_x[r] : 0.f;
                        py += in ? acc_y[r] : 0.f;
                        pz += in ? acc_z[r] : 0.f;
                    }
                    ps += __shfl_xor(ps, 16); ps += __shfl_xor(ps, 32);
                    px += __shfl_xor(px, 16); px += __shfl_xor(px, 32);
                    py += __shfl_xor(py, 16); py += __shfl_xor(py, 32);
                    pz += __shfl_xor(pz, 16); pz += __shfl_xor(pz, 32);
                    int node = __shfl(myR, lo);
                    float val = (q == 0) ? ps : (q == 1) ? px : (q == 2) ? py : pz;
                    atomicAdd(acc + (size_t)node * 64 + m * 4 + q, val);
                }

                rc = nrc;
            }
        }
        gbar(barIdx++);   // edge phase l complete

        if (l < 2) {
            // -------- gate phase: acc -> fp16 (xALPHA), rezero acc --------
            float4* accv = (float4*)acc;
            h16x4* fo = (h16x4*)foutp;
            for (int i = tid; i < N_NODES * 16; i += MEGA_THREADS) {
                float4 f = accv[i];
                float g = ALPHA / (1.f + __expf(-f.x));
                h16x4 o;
                o.x = (_Float16)(f.x * g);
                o.y = (_Float16)(f.y * g);
                o.z = (_Float16)(f.z * g);
                o.w = (_Float16)(f.w * g);
                fo[i] = o;
                accv[i] = make_float4(0.f, 0.f, 0.f, 0.f);
            }
            // ping-pong
            const _Float16* tmp = finp; finp = foutp; foutp = (_Float16*)tmp;
            gbar(barIdx++);   // gate l complete
        } else {
            // -------- readout phase --------
            float* bins = (float*)smraw;   // edge phase done; LDS reusable
            if (t < N_GRAPHS) bins[t] = 0.f;
            __syncthreads();
            for (int n = tid; n < N_NODES; n += MEGA_THREADS) {
                const float4* f = (const float4*)acc + (size_t)n * 16;
                float a = 0.f;
#pragma unroll
                for (int w = 0; w < 16; ++w) {
                    float s = f[w].x;
                    float silu = s / (1.f + __expf(-s));
                    a += silu * w_out[w];
                }
                atomicAdd(&bins[batch_idx[n]], a * INV_LIN_OUT);
            }
            __syncthreads();
            if (t < N_GRAPHS) atomicAdd(&energy[t], bins[t]);
        }
    }
}

extern "C" void kernel_launch(void* const* d_in, const int* in_sizes, int n_in,
                              void* d_out, int out_size, void* d_ws, size_t ws_size,
                              hipStream_t stream) {
    const float* x         = (const float*)d_in[0];
    const int*   row       = (const int*)d_in[1];
    const int*   col       = (const int*)d_in[2];
    const int*   batch_idx = (const int*)d_in[3];
    const float* w_in0     = (const float*)d_in[4];
    const float* w_in1     = (const float*)d_in[5];
    const float* tp_w      = (const float*)d_in[6];   // [3][5][16][16][16]
    const float* w_out0    = (const float*)d_in[7];
    float* energy = (float*)d_out;

    // workspace layout (28.1 MB total)
    float*    acc   = (float*)d_ws;                        // [N][64] f32 accum
    _Float16* featA = (_Float16*)(acc + (size_t)N_NODES * 64);   // [N][64] f16
    _Float16* featB = featA + (size_t)N_NODES * 64;              // [N][64] f16
    _Float16* wh    = featB + (size_t)N_NODES * 64;              // [3][20480] f16
    int* sortedRC = (int*)(wh + 3 * 20480);                // [E] packed (row | col<<16)
    int* counts  = (int*)featB;   // transient sort scratch (dead until gate0)

    // dispatch 1: proj -> featA (fp16), swizzle -> wh, zero counts/energy/acc/bars
    init_kernel<<<(3 * 20480 + 255) / 256, 256, 0, stream>>>(
        x, w_in0, w_in1, tp_w, (h16x4*)featA, wh, counts, energy, (float4*)acc);

    // dispatch 2: everything else, grid-barrier separated
    mega_kernel<<<MEGA_GRID, 256, 0, stream>>>(
        row, col, batch_idx, w_out0, wh, acc, featA, featB, sortedRC, energy);
}

// Round 7
// 808.882 us; speedup vs baseline: 5.9188x; 3.6809x over previous
//
#include <hip/hip_runtime.h>

#define N_NODES 50000
#define N_EDGES 600000
#define N_GRAPHS 64
#define N_TILES (N_EDGES / 16)   // 37500 wave-tiles
#define NPART 196                // ceil(50000/256) scan partials

// constants
#define INV_LIN_IN  0.35355339059327373f   // 1/sqrt(8)
#define INV_LIN_OUT 0.25f                  // 1/sqrt(16)
#define C_INV_S3    0.5773502691896258f    // 1/sqrt(3)
#define C_INV_S2    0.7071067811865476f    // 1/sqrt(2)
#define C_NORM_S    0.04419417382415922f   // 1/sqrt(512)
#define C_NORM_V    0.036084391824351615f  // 1/sqrt(768)

// fp16 overflow guard: features entering layers 1,2 are scaled by ALPHA after
// the gate; the inverse (1/ALPHA^2 = 1024) is folded into those layers' weights.
#define ALPHA      0.03125f                // 1/32
#define W_UNSCALE  1024.0f                 // 1/ALPHA^2

typedef __attribute__((ext_vector_type(8))) _Float16 h16x8;
typedef __attribute__((ext_vector_type(4))) _Float16 h16x4;
typedef __attribute__((ext_vector_type(2))) _Float16 h16x2;
typedef __attribute__((ext_vector_type(4))) float f32x4;

// grid-barrier counters: one slot per phase boundary, zeroed by init each launch
__device__ int g_bars[16];

// Device-scope barrier, R6-postmortem version:
//  - RELEASE fetch_add publishes this block's writes (writeback to coherence pt)
//  - spin on RELAXED load (reads coherence point, NO per-poll L2 invalidate —
//    R6's acquire-per-poll cost ~295 us/barrier in serialized cache-maintenance)
//  - ONE acquire load after exit invalidates stale caches, then __syncthreads
//    orders it before any wave's subsequent reads.
__device__ __forceinline__ void gbar(int idx) {
    __syncthreads();
    if (threadIdx.x == 0) {
        __hip_atomic_fetch_add(&g_bars[idx], 1, __ATOMIC_RELEASE, __HIP_MEMORY_SCOPE_AGENT);
        while (__hip_atomic_load(&g_bars[idx], __ATOMIC_RELAXED, __HIP_MEMORY_SCOPE_AGENT)
               < (int)gridDim.x)
            __builtin_amdgcn_s_sleep(16);
        (void)__hip_atomic_load(&g_bars[idx], __ATOMIC_ACQUIRE, __HIP_MEMORY_SCOPE_AGENT);
    }
    __syncthreads();
}

// -------------------- fused init: proj (fp16 out) + weight swizzle (fp16) +
// counts/energy/acc/barrier zero.
__global__ void init_kernel(const float* __restrict__ x,
                            const float* __restrict__ w_in0,
                            const float* __restrict__ w_in1,
                            const float* __restrict__ tp_w,
                            h16x4* __restrict__ featH,
                            _Float16* __restrict__ wh,
                            int* __restrict__ counts,
                            float* __restrict__ energy,
                            float4* __restrict__ acc) {
    int gid = blockIdx.x * 256 + threadIdx.x;

    if (gid < 16) g_bars[gid] = 0;
    if (gid < 64) energy[gid] = 0.f;
    if (gid < N_NODES) counts[gid] = 0;

    // zero the f32 accumulator: 800k float4 over 61440 threads (grid-stride)
    for (int idx = gid; idx < N_NODES * 16; idx += 61440)
        acc[idx] = make_float4(0.f, 0.f, 0.f, 0.f);

    if (gid < 3 * 20480) {   // weight swizzle -> fp16 (one-time cost)
        int i = gid;
        int j    = i & 7;
        int t1   = i >> 3;
        int lane = t1 & 63;
        int t2   = t1 >> 6;
        int c    = t2 & 7;
        int t3   = t2 >> 3;
        int slot = t3 % 5;
        int l    = t3 / 5;
        int p = (slot == 0) ? 1 : (slot == 1) ? 2 : (slot == 2) ? 4 : (slot == 3) ? 0 : 3;
        int kk = c * 32 + (lane >> 4) * 8 + j;
        int u = kk >> 4, v = kk & 15, n = lane & 15;
        float scale;
        if      (p == 0) scale = C_NORM_S;
        else if (p == 3) scale = C_INV_S3 * C_NORM_S;
        else if (p == 4) scale = C_INV_S2 * C_NORM_V;
        else             scale = C_NORM_V;   // p==1, p==2
        if (l > 0) scale *= W_UNSCALE;       // undo ALPHA^2 feature pre-scale
        float val = tp_w[(size_t)(l * 5 + p) * 4096 + u * 256 + v * 16 + n] * scale;
        wh[i] = (_Float16)val;
    }

    if (gid < N_NODES) {     // input projection -> fp16 features (layer-0: unscaled)
        const float* xp = x + (size_t)gid * 32;
        float xs[8], xvx[8], xvy[8], xvz[8];
#pragma unroll
        for (int u = 0; u < 8; ++u) xs[u] = xp[u];
#pragma unroll
        for (int u = 0; u < 8; ++u) {
            xvx[u] = xp[8 + 3 * u + 0];
            xvy[u] = xp[8 + 3 * u + 1];
            xvz[u] = xp[8 + 3 * u + 2];
        }
#pragma unroll
        for (int w = 0; w < 16; ++w) {
            float s = 0.f, vx = 0.f, vy = 0.f, vz = 0.f;
#pragma unroll
            for (int u = 0; u < 8; ++u) {
                float a0 = w_in0[u * 16 + w];
                float a1 = w_in1[u * 16 + w];
                s  += xs[u]  * a0;
                vx += xvx[u] * a1;
                vy += xvy[u] * a1;
                vz += xvz[u] * a1;
            }
            h16x4 o;
            o.x = (_Float16)(s  * INV_LIN_IN);
            o.y = (_Float16)(vx * INV_LIN_IN);
            o.z = (_Float16)(vy * INV_LIN_IN);
            o.w = (_Float16)(vz * INV_LIN_IN);
            featH[(size_t)gid * 16 + w] = o;
        }
    }
}

// ==================== MEGA persistent kernel ====================
// Phases: hist | scan_part | scan_final | scatter | 3x(edge [+gate]) | readout
// separated by device-scope grid barriers. Grid is computed at launch as the
// EXACT measured residency (hipOccupancyMaxActiveBlocksPerMultiprocessor), and
// the barrier target is gridDim.x — deadlock-impossible by construction.
__global__ __launch_bounds__(256, 4)
void mega_kernel(const int* __restrict__ row, const int* __restrict__ col,
                 const int* __restrict__ batch_idx,
                 const float* __restrict__ w_out,
                 const _Float16* __restrict__ wh,
                 float* __restrict__ acc,
                 _Float16* __restrict__ featA,
                 _Float16* __restrict__ featB,
                 int* __restrict__ sortedRC,
                 float* __restrict__ energy) {
    __shared__ __align__(16) char smraw[16384];

    const int t   = threadIdx.x;
    const int tid = blockIdx.x * 256 + t;
    const int nthreads = (int)gridDim.x * 256;

    // sort scratch aliased into featB (dead until gate0 writes featB at bar 5)
    int* counts  = (int*)featB;
    int* cursor  = counts + N_NODES;
    int* partial = cursor + N_NODES;

    // ---------- P0: histogram ----------
    for (int e = tid; e < N_EDGES; e += nthreads)
        atomicAdd(&counts[row[e]], 1);
    gbar(0);

    // ---------- P1: per-256-chunk sums ----------
    if (blockIdx.x < NPART) {
        int* sm = (int*)smraw;
        int i = blockIdx.x * 256 + t;
        sm[t] = (i < N_NODES) ? counts[i] : 0;
        __syncthreads();
        for (int s = 128; s > 0; s >>= 1) {
            if (t < s) sm[t] += sm[t + s];
            __syncthreads();
        }
        if (t == 0) partial[blockIdx.x] = sm[0];
    }
    gbar(1);

    // ---------- P2: final exclusive scan ----------
    if (blockIdx.x < NPART) {
        int* sm  = (int*)smraw;
        int* sm2 = sm + 256;
        int i = blockIdx.x * 256 + t;
        int v = (i < N_NODES) ? counts[i] : 0;
        sm[t] = v;
        sm2[t] = (t < NPART && t < blockIdx.x) ? partial[t] : 0;
        __syncthreads();
        for (int s = 128; s > 0; s >>= 1) {
            if (t < s) sm2[t] += sm2[t + s];
            __syncthreads();
        }
        int base = sm2[0];
        for (int s = 1; s < 256; s <<= 1) {
            int add = (t >= s) ? sm[t - s] : 0;
            __syncthreads();
            sm[t] += add;
            __syncthreads();
        }
        if (i < N_NODES) cursor[i] = sm[t] - v + base;
    }
    gbar(2);

    // ---------- P3: scatter into destination-sorted order ----------
    for (int e = tid; e < N_EDGES; e += nthreads) {
        int n = row[e];
        int pos = atomicAdd(&cursor[n], 1);
        sortedRC[pos] = n | (col[e] << 16);   // node ids < 50000 < 65536
    }
    gbar(3);

    // ---------- layers ----------
    const int lane = t & 63;
    const int wave = t >> 6;
    const int q = lane >> 4;        // quad 0..3
    const int m = lane & 15;        // edge-in-tile / w column
    const int v0 = (q & 1) * 8;
    const int gw_id = blockIdx.x * 4 + wave;
    const int nw = (int)gridDim.x * 4;
    const int tile0   = (int)(((long long)gw_id * N_TILES) / nw);
    const int tileEnd = (int)(((long long)(gw_id + 1) * N_TILES) / nw);

    const _Float16* finp = featA;
    _Float16* foutp = featB;
    int barIdx = 4;

    for (int l = 0; l < 3; ++l) {
        // refill LDS with this layer's paths {1,2}
        const _Float16* whl = wh + (size_t)l * 20480;
        {
            const int4* src = (const int4*)whl;
            int4* dst = (int4*)smraw;
#pragma unroll
            for (int i = 0; i < 4; ++i) dst[t + 256 * i] = src[t + 256 * i];
        }
        __syncthreads();
        const h16x8* sW = (const h16x8*)smraw;
        const h16x8* gw = ((const h16x8*)whl) + 1024;   // paths {4,0,3} in global
        const h16x4* feat = (const h16x4*)finp;

        // -------- edge tensor-product phase (identical to R4's proven loop) ----
        if (tile0 < tileEnd) {
            int tile = tile0;
            int rc = sortedRC[tile * 16 + m];
            h16x4 Bt[8];
            {
                const h16x4* bp = feat + (size_t)(((unsigned)rc) >> 16) * 16 + v0;
#pragma unroll
                for (int k = 0; k < 8; ++k) Bt[k] = bp[k];
            }

            for (; tile < tileEnd; ++tile) {
                const int myR = rc & 0xFFFF;
                const int nt = tile + 1;
                const int nrc = (nt < tileEnd) ? sortedRC[nt * 16 + m] : rc;

                h16x2 Bs[4], Bx[4], By[4], Bz[4];
#pragma unroll
                for (int k = 0; k < 4; ++k) {
                    Bs[k].x = Bt[2 * k].x; Bs[k].y = Bt[2 * k + 1].x;
                    Bx[k].x = Bt[2 * k].y; Bx[k].y = Bt[2 * k + 1].y;
                    By[k].x = Bt[2 * k].z; By[k].y = Bt[2 * k + 1].z;
                    Bz[k].x = Bt[2 * k].w; Bz[k].y = Bt[2 * k + 1].w;
                }

                f32x4 acc_s = {0.f, 0.f, 0.f, 0.f};
                f32x4 acc_x = {0.f, 0.f, 0.f, 0.f};
                f32x4 acc_y = {0.f, 0.f, 0.f, 0.f};
                f32x4 acc_z = {0.f, 0.f, 0.f, 0.f};

                const h16x4* ap = feat + (size_t)myR * 16;

#pragma unroll 4
                for (int c = 0; c < 8; ++c) {
                    h16x8 w4f = gw[(0 * 8 + c) * 64 + lane];   // path 4 (cross)
                    h16x8 w0f = gw[(1 * 8 + c) * 64 + lane];   // path 0 (ss)
                    h16x8 w3f = gw[(2 * 8 + c) * 64 + lane];   // path 3 (dot)
                    h16x8 w1f = sW[(0 * 8 + c) * 64 + lane];
                    h16x8 w2f = sW[(1 * 8 + c) * 64 + lane];

                    h16x4 A = ap[2 * c + (q >> 1)];   // L1-hot (sorted rows)
                    h16x2 s2; s2.x = A.x; s2.y = A.x;
                    h16x2 x2; x2.x = A.y; x2.y = A.y;
                    h16x2 y2; y2.x = A.z; y2.y = A.z;
                    h16x2 z2; z2.x = A.w; z2.y = A.w;

                    union { h16x8 v; h16x2 h[4]; } z;

#pragma unroll
                    for (int k = 0; k < 4; ++k) z.h[k] = s2 * Bs[k];
                    acc_s = __builtin_amdgcn_mfma_f32_16x16x32_f16(z.v, w0f, acc_s, 0, 0, 0);

#pragma unroll
                    for (int k = 0; k < 4; ++k)
                        z.h[k] = x2 * Bx[k] + y2 * By[k] + z2 * Bz[k];
                    acc_s = __builtin_amdgcn_mfma_f32_16x16x32_f16(z.v, w3f, acc_s, 0, 0, 0);

#pragma unroll
                    for (int k = 0; k < 4; ++k) z.h[k] = s2 * Bx[k];
                    acc_x = __builtin_amdgcn_mfma_f32_16x16x32_f16(z.v, w1f, acc_x, 0, 0, 0);
#pragma unroll
                    for (int k = 0; k < 4; ++k) z.h[k] = x2 * Bs[k];
                    acc_x = __builtin_amdgcn_mfma_f32_16x16x32_f16(z.v, w2f, acc_x, 0, 0, 0);
#pragma unroll
                    for (int k = 0; k < 4; ++k) z.h[k] = y2 * Bz[k] - z2 * By[k];
                    acc_x = __builtin_amdgcn_mfma_f32_16x16x32_f16(z.v, w4f, acc_x, 0, 0, 0);

#pragma unroll
                    for (int k = 0; k < 4; ++k) z.h[k] = s2 * By[k];
                    acc_y = __builtin_amdgcn_mfma_f32_16x16x32_f16(z.v, w1f, acc_y, 0, 0, 0);
#pragma unroll
                    for (int k = 0; k < 4; ++k) z.h[k] = y2 * Bs[k];
                    acc_y = __builtin_amdgcn_mfma_f32_16x16x32_f16(z.v, w2f, acc_y, 0, 0, 0);
#pragma unroll
                    for (int k = 0; k < 4; ++k) z.h[k] = z2 * Bx[k] - x2 * Bz[k];
                    acc_y = __builtin_amdgcn_mfma_f32_16x16x32_f16(z.v, w4f, acc_y, 0, 0, 0);

#pragma unroll
                    for (int k = 0; k < 4; ++k) z.h[k] = s2 * Bz[k];
                    acc_z = __builtin_amdgcn_mfma_f32_16x16x32_f16(z.v, w1f, acc_z, 0, 0, 0);
#pragma unroll
                    for (int k = 0; k < 4; ++k) z.h[k] = z2 * Bs[k];
                    acc_z = __builtin_amdgcn_mfma_f32_16x16x32_f16(z.v, w2f, acc_z, 0, 0, 0);
#pragma unroll
                    for (int k = 0; k < 4; ++k) z.h[k] = x2 * By[k] - y2 * Bx[k];
                    acc_z = __builtin_amdgcn_mfma_f32_16x16x32_f16(z.v, w4f, acc_z, 0, 0, 0);
                }

                // prefetch next tile's B
                {
                    const h16x4* nbp = feat + (size_t)(((unsigned)nrc) >> 16) * 16 + v0;
#pragma unroll
                    for (int k = 0; k < 8; ++k) Bt[k] = nbp[k];
                }

                // wave-local segmented epilogue
                int prevR = __shfl(myR, (lane + 63) & 63);
                int flag = (m == 0) || (myR != prevR);
                unsigned long long bal = __ballot(flag != 0);
                unsigned mask16 = (unsigned)(bal & 0xFFFFull);

                int nseg = __popc(mask16);
                unsigned rem = mask16;
                for (int s = 0; s < nseg; ++s) {
                    int lo = __ffs(rem) - 1;
                    rem &= rem - 1;
                    int hi = rem ? (__ffs(rem) - 1) : 16;
                    float ps = 0.f, px = 0.f, py = 0.f, pz = 0.f;
#pragma unroll
                    for (int r = 0; r < 4; ++r) {
                        int ei = q * 4 + r;
                        bool in = (ei >= lo) && (ei < hi);
                        ps += in ? acc_s[r] : 0.f;
                        px += in ? acc_x[r] : 0.f;
                        py += in ? acc_y[r] : 0.f;
                        pz += in ? acc_z[r] : 0.f;
                    }
                    ps += __shfl_xor(ps, 16); ps += __shfl_xor(ps, 32);
                    px += __shfl_xor(px, 16); px += __shfl_xor(px, 32);
                    py += __shfl_xor(py, 16); py += __shfl_xor(py, 32);
                    pz += __shfl_xor(pz, 16); pz += __shfl_xor(pz, 32);
                    int node = __shfl(myR, lo);
                    float val = (q == 0) ? ps : (q == 1) ? px : (q == 2) ? py : pz;
                    atomicAdd(acc + (size_t)node * 64 + m * 4 + q, val);
                }

                rc = nrc;
            }
        }
        gbar(barIdx++);   // edge phase l complete

        if (l < 2) {
            // -------- gate phase: acc -> fp16 (xALPHA), rezero acc --------
            float4* accv = (float4*)acc;
            h16x4* fo = (h16x4*)foutp;
            for (int i = tid; i < N_NODES * 16; i += nthreads) {
                float4 f = accv[i];
                float g = ALPHA / (1.f + __expf(-f.x));
                h16x4 o;
                o.x = (_Float16)(f.x * g);
                o.y = (_Float16)(f.y * g);
                o.z = (_Float16)(f.z * g);
                o.w = (_Float16)(f.w * g);
                fo[i] = o;
                accv[i] = make_float4(0.f, 0.f, 0.f, 0.f);
            }
            // ping-pong
            const _Float16* tmp = finp; finp = foutp; foutp = (_Float16*)tmp;
            gbar(barIdx++);   // gate l complete
        } else {
            // -------- readout phase --------
            float* bins = (float*)smraw;   // edge phase done; LDS reusable
            if (t < N_GRAPHS) bins[t] = 0.f;
            __syncthreads();
            for (int n = tid; n < N_NODES; n += nthreads) {
                const float4* f = (const float4*)acc + (size_t)n * 16;
                float a = 0.f;
#pragma unroll
                for (int w = 0; w < 16; ++w) {
                    float s = f[w].x;
                    float silu = s / (1.f + __expf(-s));
                    a += silu * w_out[w];
                }
                atomicAdd(&bins[batch_idx[n]], a * INV_LIN_OUT);
            }
            __syncthreads();
            if (t < N_GRAPHS) atomicAdd(&energy[t], bins[t]);
        }
    }
}

extern "C" void kernel_launch(void* const* d_in, const int* in_sizes, int n_in,
                              void* d_out, int out_size, void* d_ws, size_t ws_size,
                              hipStream_t stream) {
    const float* x         = (const float*)d_in[0];
    const int*   row       = (const int*)d_in[1];
    const int*   col       = (const int*)d_in[2];
    const int*   batch_idx = (const int*)d_in[3];
    const float* w_in0     = (const float*)d_in[4];
    const float* w_in1     = (const float*)d_in[5];
    const float* tp_w      = (const float*)d_in[6];   // [3][5][16][16][16]
    const float* w_out0    = (const float*)d_in[7];
    float* energy = (float*)d_out;

    // workspace layout (28.1 MB total)
    float*    acc   = (float*)d_ws;                        // [N][64] f32 accum
    _Float16* featA = (_Float16*)(acc + (size_t)N_NODES * 64);   // [N][64] f16
    _Float16* featB = featA + (size_t)N_NODES * 64;              // [N][64] f16
    _Float16* wh    = featB + (size_t)N_NODES * 64;              // [3][20480] f16
    int* sortedRC = (int*)(wh + 3 * 20480);                // [E] packed (row | col<<16)
    int* counts  = (int*)featB;   // transient sort scratch (dead until gate0)

    // grid = exact measured residency (once; pure driver query, no stream ops).
    // Barrier target is gridDim.x, so this is deadlock-free by construction.
    static int megaGrid = 0;
    if (megaGrid == 0) {
        int nb = 0;
        hipError_t err = hipOccupancyMaxActiveBlocksPerMultiprocessor(
            &nb, mega_kernel, 256, 0);
        if (err != hipSuccess || nb < 1) nb = 4;   // (256,4) bound guarantees 4
        if (nb > 8) nb = 8;                         // 32-wave/CU cap
        megaGrid = nb * 256;                        // 256 CUs on MI355X
        if (megaGrid < 256) megaGrid = 256;         // >= NPART for scan phases
    }

    // dispatch 1: proj -> featA (fp16), swizzle -> wh, zero counts/energy/acc/bars
    init_kernel<<<(3 * 20480 + 255) / 256, 256, 0, stream>>>(
        x, w_in0, w_in1, tp_w, (h16x4*)featA, wh, counts, energy, (float4*)acc);

    // dispatch 2: everything else, grid-barrier separated
    mega_kernel<<<megaGrid, 256, 0, stream>>>(
        row, col, batch_idx, w_out0, wh, acc, featA, featB, sortedRC, energy);
}

// Round 8
// 748.167 us; speedup vs baseline: 6.3992x; 1.0812x over previous
//
#include <hip/hip_runtime.h>

#define N_NODES 50000
#define N_EDGES 600000
#define N_GRAPHS 64
#define N_TILES (N_EDGES / 16)   // 37500 wave-tiles
#define NPART 196                // ceil(50000/256) scan partials
#define NGRP 64                  // barrier groups (each counter/flag on own 128B line)

// constants
#define INV_LIN_IN  0.35355339059327373f   // 1/sqrt(8)
#define INV_LIN_OUT 0.25f                  // 1/sqrt(16)
#define C_INV_S3    0.5773502691896258f    // 1/sqrt(3)
#define C_INV_S2    0.7071067811865476f    // 1/sqrt(2)
#define C_NORM_S    0.04419417382415922f   // 1/sqrt(512)
#define C_NORM_V    0.036084391824351615f  // 1/sqrt(768)

// fp16 overflow guard: features entering layers 1,2 are scaled by ALPHA after
// the gate; the inverse (1/ALPHA^2 = 1024) is folded into those layers' weights.
#define ALPHA      0.03125f                // 1/32
#define W_UNSCALE  1024.0f                 // 1/ALPHA^2

typedef __attribute__((ext_vector_type(8))) _Float16 h16x8;
typedef __attribute__((ext_vector_type(4))) _Float16 h16x4;
typedef __attribute__((ext_vector_type(2))) _Float16 h16x2;
typedef __attribute__((ext_vector_type(4))) float f32x4;

// Hierarchical barrier state: per-phase, per-group counters/flags, each padded
// to a 128B line so RMWs/polls on different groups never share a line.
// R7 lesson: ONE line polled by 2048 leaders saturates its LLC slice (~83us/bar).
__device__ int g_grpCnt[16][NGRP][32];
__device__ int g_glbCnt[16][32];
__device__ int g_flag[16][NGRP][32];

// Two-level device-scope barrier:
//   arrive:  32 RMWs on own group line -> last member RMWs the global line (64)
//   notify:  64th group-completer writes the 64 flag lines
//   wait:    leaders poll ONLY their group's flag line (32 pollers/line, relaxed),
//            one acquire load after exit invalidates stale caches.
__device__ __forceinline__ void gbar(int idx) {
    __syncthreads();
    if (threadIdx.x == 0) {
        const int grp  = blockIdx.x & (NGRP - 1);
        const int nmem = (int)gridDim.x >> 6;   // gridDim multiple of 64
        int r = __hip_atomic_fetch_add(&g_grpCnt[idx][grp][0], 1,
                                       __ATOMIC_ACQ_REL, __HIP_MEMORY_SCOPE_AGENT);
        if (r == nmem - 1) {
            int g = __hip_atomic_fetch_add(&g_glbCnt[idx][0], 1,
                                           __ATOMIC_ACQ_REL, __HIP_MEMORY_SCOPE_AGENT);
            if (g == NGRP - 1) {
#pragma unroll 4
                for (int i = 0; i < NGRP; ++i)
                    __hip_atomic_store(&g_flag[idx][i][0], 1,
                                       __ATOMIC_RELEASE, __HIP_MEMORY_SCOPE_AGENT);
            }
        }
        while (__hip_atomic_load(&g_flag[idx][grp][0], __ATOMIC_RELAXED,
                                 __HIP_MEMORY_SCOPE_AGENT) == 0)
            __builtin_amdgcn_s_sleep(32);
        (void)__hip_atomic_load(&g_flag[idx][grp][0], __ATOMIC_ACQUIRE,
                                __HIP_MEMORY_SCOPE_AGENT);
    }
    __syncthreads();
}

// -------------------- fused init: proj (fp16 out) + weight swizzle (fp16) +
// counts/energy/acc/barrier-state zero.
__global__ void init_kernel(const float* __restrict__ x,
                            const float* __restrict__ w_in0,
                            const float* __restrict__ w_in1,
                            const float* __restrict__ tp_w,
                            h16x4* __restrict__ featH,
                            _Float16* __restrict__ wh,
                            int* __restrict__ counts,
                            float* __restrict__ energy,
                            float4* __restrict__ acc) {
    int gid = blockIdx.x * 256 + threadIdx.x;

    // zero barrier state (per-replay; graph-capture safe)
    if (gid < 16 * NGRP) {
        g_grpCnt[gid >> 6][gid & (NGRP - 1)][0] = 0;
        g_flag[gid >> 6][gid & (NGRP - 1)][0] = 0;
    }
    if (gid < 16) g_glbCnt[gid][0] = 0;

    if (gid < 64) energy[gid] = 0.f;
    if (gid < N_NODES) counts[gid] = 0;

    // zero the f32 accumulator: 800k float4 over 61440 threads (grid-stride)
    for (int idx = gid; idx < N_NODES * 16; idx += 61440)
        acc[idx] = make_float4(0.f, 0.f, 0.f, 0.f);

    if (gid < 3 * 20480) {   // weight swizzle -> fp16 (one-time cost)
        int i = gid;
        int j    = i & 7;
        int t1   = i >> 3;
        int lane = t1 & 63;
        int t2   = t1 >> 6;
        int c    = t2 & 7;
        int t3   = t2 >> 3;
        int slot = t3 % 5;
        int l    = t3 / 5;
        int p = (slot == 0) ? 1 : (slot == 1) ? 2 : (slot == 2) ? 4 : (slot == 3) ? 0 : 3;
        int kk = c * 32 + (lane >> 4) * 8 + j;
        int u = kk >> 4, v = kk & 15, n = lane & 15;
        float scale;
        if      (p == 0) scale = C_NORM_S;
        else if (p == 3) scale = C_INV_S3 * C_NORM_S;
        else if (p == 4) scale = C_INV_S2 * C_NORM_V;
        else             scale = C_NORM_V;   // p==1, p==2
        if (l > 0) scale *= W_UNSCALE;       // undo ALPHA^2 feature pre-scale
        float val = tp_w[(size_t)(l * 5 + p) * 4096 + u * 256 + v * 16 + n] * scale;
        wh[i] = (_Float16)val;
    }

    if (gid < N_NODES) {     // input projection -> fp16 features (layer-0: unscaled)
        const float* xp = x + (size_t)gid * 32;
        float xs[8], xvx[8], xvy[8], xvz[8];
#pragma unroll
        for (int u = 0; u < 8; ++u) xs[u] = xp[u];
#pragma unroll
        for (int u = 0; u < 8; ++u) {
            xvx[u] = xp[8 + 3 * u + 0];
            xvy[u] = xp[8 + 3 * u + 1];
            xvz[u] = xp[8 + 3 * u + 2];
        }
#pragma unroll
        for (int w = 0; w < 16; ++w) {
            float s = 0.f, vx = 0.f, vy = 0.f, vz = 0.f;
#pragma unroll
            for (int u = 0; u < 8; ++u) {
                float a0 = w_in0[u * 16 + w];
                float a1 = w_in1[u * 16 + w];
                s  += xs[u]  * a0;
                vx += xvx[u] * a1;
                vy += xvy[u] * a1;
                vz += xvz[u] * a1;
            }
            h16x4 o;
            o.x = (_Float16)(s  * INV_LIN_IN);
            o.y = (_Float16)(vx * INV_LIN_IN);
            o.z = (_Float16)(vy * INV_LIN_IN);
            o.w = (_Float16)(vz * INV_LIN_IN);
            featH[(size_t)gid * 16 + w] = o;
        }
    }
}

// ==================== MEGA persistent kernel ====================
// Phases: hist | scan_part | scan_final | scatter | 3x(edge [+gate]) | readout
// separated by hierarchical device-scope grid barriers. Grid = exact measured
// residency (occupancy query), rounded to a multiple of 64 — barrier target is
// gridDim.x, deadlock-impossible by construction.
__global__ __launch_bounds__(256, 4)
void mega_kernel(const int* __restrict__ row, const int* __restrict__ col,
                 const int* __restrict__ batch_idx,
                 const float* __restrict__ w_out,
                 const _Float16* __restrict__ wh,
                 float* __restrict__ acc,
                 _Float16* __restrict__ featA,
                 _Float16* __restrict__ featB,
                 int* __restrict__ sortedRC,
                 float* __restrict__ energy) {
    __shared__ __align__(16) char smraw[16384];

    const int t   = threadIdx.x;
    const int tid = blockIdx.x * 256 + t;
    const int nthreads = (int)gridDim.x * 256;

    // sort scratch aliased into featB (dead until gate0 writes featB at bar 5)
    int* counts  = (int*)featB;
    int* cursor  = counts + N_NODES;
    int* partial = cursor + N_NODES;

    // ---------- P0: histogram ----------
    for (int e = tid; e < N_EDGES; e += nthreads)
        atomicAdd(&counts[row[e]], 1);
    gbar(0);

    // ---------- P1: per-256-chunk sums ----------
    if (blockIdx.x < NPART) {
        int* sm = (int*)smraw;
        int i = blockIdx.x * 256 + t;
        sm[t] = (i < N_NODES) ? counts[i] : 0;
        __syncthreads();
        for (int s = 128; s > 0; s >>= 1) {
            if (t < s) sm[t] += sm[t + s];
            __syncthreads();
        }
        if (t == 0) partial[blockIdx.x] = sm[0];
    }
    gbar(1);

    // ---------- P2: final exclusive scan ----------
    if (blockIdx.x < NPART) {
        int* sm  = (int*)smraw;
        int* sm2 = sm + 256;
        int i = blockIdx.x * 256 + t;
        int v = (i < N_NODES) ? counts[i] : 0;
        sm[t] = v;
        sm2[t] = (t < NPART && t < blockIdx.x) ? partial[t] : 0;
        __syncthreads();
        for (int s = 128; s > 0; s >>= 1) {
            if (t < s) sm2[t] += sm2[t + s];
            __syncthreads();
        }
        int base = sm2[0];
        for (int s = 1; s < 256; s <<= 1) {
            int add = (t >= s) ? sm[t - s] : 0;
            __syncthreads();
            sm[t] += add;
            __syncthreads();
        }
        if (i < N_NODES) cursor[i] = sm[t] - v + base;
    }
    gbar(2);

    // ---------- P3: scatter into destination-sorted order ----------
    for (int e = tid; e < N_EDGES; e += nthreads) {
        int n = row[e];
        int pos = atomicAdd(&cursor[n], 1);
        sortedRC[pos] = n | (col[e] << 16);   // node ids < 50000 < 65536
    }
    gbar(3);

    // ---------- layers ----------
    const int lane = t & 63;
    const int wave = t >> 6;
    const int q = lane >> 4;        // quad 0..3
    const int m = lane & 15;        // edge-in-tile / w column
    const int v0 = (q & 1) * 8;
    const int gw_id = blockIdx.x * 4 + wave;
    const int nw = (int)gridDim.x * 4;
    const int tile0   = (int)(((long long)gw_id * N_TILES) / nw);
    const int tileEnd = (int)(((long long)(gw_id + 1) * N_TILES) / nw);

    const _Float16* finp = featA;
    _Float16* foutp = featB;
    int barIdx = 4;

    for (int l = 0; l < 3; ++l) {
        // refill LDS with this layer's paths {1,2}
        const _Float16* whl = wh + (size_t)l * 20480;
        {
            const int4* src = (const int4*)whl;
            int4* dst = (int4*)smraw;
#pragma unroll
            for (int i = 0; i < 4; ++i) dst[t + 256 * i] = src[t + 256 * i];
        }
        __syncthreads();
        const h16x8* sW = (const h16x8*)smraw;
        const h16x8* gw = ((const h16x8*)whl) + 1024;   // paths {4,0,3} in global
        const h16x4* feat = (const h16x4*)finp;

        // -------- edge tensor-product phase (identical to R4's proven loop) ----
        if (tile0 < tileEnd) {
            int tile = tile0;
            int rc = sortedRC[tile * 16 + m];
            h16x4 Bt[8];
            {
                const h16x4* bp = feat + (size_t)(((unsigned)rc) >> 16) * 16 + v0;
#pragma unroll
                for (int k = 0; k < 8; ++k) Bt[k] = bp[k];
            }

            for (; tile < tileEnd; ++tile) {
                const int myR = rc & 0xFFFF;
                const int nt = tile + 1;
                const int nrc = (nt < tileEnd) ? sortedRC[nt * 16 + m] : rc;

                h16x2 Bs[4], Bx[4], By[4], Bz[4];
#pragma unroll
                for (int k = 0; k < 4; ++k) {
                    Bs[k].x = Bt[2 * k].x; Bs[k].y = Bt[2 * k + 1].x;
                    Bx[k].x = Bt[2 * k].y; Bx[k].y = Bt[2 * k + 1].y;
                    By[k].x = Bt[2 * k].z; By[k].y = Bt[2 * k + 1].z;
                    Bz[k].x = Bt[2 * k].w; Bz[k].y = Bt[2 * k + 1].w;
                }

                f32x4 acc_s = {0.f, 0.f, 0.f, 0.f};
                f32x4 acc_x = {0.f, 0.f, 0.f, 0.f};
                f32x4 acc_y = {0.f, 0.f, 0.f, 0.f};
                f32x4 acc_z = {0.f, 0.f, 0.f, 0.f};

                const h16x4* ap = feat + (size_t)myR * 16;

#pragma unroll 4
                for (int c = 0; c < 8; ++c) {
                    h16x8 w4f = gw[(0 * 8 + c) * 64 + lane];   // path 4 (cross)
                    h16x8 w0f = gw[(1 * 8 + c) * 64 + lane];   // path 0 (ss)
                    h16x8 w3f = gw[(2 * 8 + c) * 64 + lane];   // path 3 (dot)
                    h16x8 w1f = sW[(0 * 8 + c) * 64 + lane];
                    h16x8 w2f = sW[(1 * 8 + c) * 64 + lane];

                    h16x4 A = ap[2 * c + (q >> 1)];   // L1-hot (sorted rows)
                    h16x2 s2; s2.x = A.x; s2.y = A.x;
                    h16x2 x2; x2.x = A.y; x2.y = A.y;
                    h16x2 y2; y2.x = A.z; y2.y = A.z;
                    h16x2 z2; z2.x = A.w; z2.y = A.w;

                    union { h16x8 v; h16x2 h[4]; } z;

#pragma unroll
                    for (int k = 0; k < 4; ++k) z.h[k] = s2 * Bs[k];
                    acc_s = __builtin_amdgcn_mfma_f32_16x16x32_f16(z.v, w0f, acc_s, 0, 0, 0);

#pragma unroll
                    for (int k = 0; k < 4; ++k)
                        z.h[k] = x2 * Bx[k] + y2 * By[k] + z2 * Bz[k];
                    acc_s = __builtin_amdgcn_mfma_f32_16x16x32_f16(z.v, w3f, acc_s, 0, 0, 0);

#pragma unroll
                    for (int k = 0; k < 4; ++k) z.h[k] = s2 * Bx[k];
                    acc_x = __builtin_amdgcn_mfma_f32_16x16x32_f16(z.v, w1f, acc_x, 0, 0, 0);
#pragma unroll
                    for (int k = 0; k < 4; ++k) z.h[k] = x2 * Bs[k];
                    acc_x = __builtin_amdgcn_mfma_f32_16x16x32_f16(z.v, w2f, acc_x, 0, 0, 0);
#pragma unroll
                    for (int k = 0; k < 4; ++k) z.h[k] = y2 * Bz[k] - z2 * By[k];
                    acc_x = __builtin_amdgcn_mfma_f32_16x16x32_f16(z.v, w4f, acc_x, 0, 0, 0);

#pragma unroll
                    for (int k = 0; k < 4; ++k) z.h[k] = s2 * By[k];
                    acc_y = __builtin_amdgcn_mfma_f32_16x16x32_f16(z.v, w1f, acc_y, 0, 0, 0);
#pragma unroll
                    for (int k = 0; k < 4; ++k) z.h[k] = y2 * Bs[k];
                    acc_y = __builtin_amdgcn_mfma_f32_16x16x32_f16(z.v, w2f, acc_y, 0, 0, 0);
#pragma unroll
                    for (int k = 0; k < 4; ++k) z.h[k] = z2 * Bx[k] - x2 * Bz[k];
                    acc_y = __builtin_amdgcn_mfma_f32_16x16x32_f16(z.v, w4f, acc_y, 0, 0, 0);

#pragma unroll
                    for (int k = 0; k < 4; ++k) z.h[k] = s2 * Bz[k];
                    acc_z = __builtin_amdgcn_mfma_f32_16x16x32_f16(z.v, w1f, acc_z, 0, 0, 0);
#pragma unroll
                    for (int k = 0; k < 4; ++k) z.h[k] = z2 * Bs[k];
                    acc_z = __builtin_amdgcn_mfma_f32_16x16x32_f16(z.v, w2f, acc_z, 0, 0, 0);
#pragma unroll
                    for (int k = 0; k < 4; ++k) z.h[k] = x2 * By[k] - y2 * Bx[k];
                    acc_z = __builtin_amdgcn_mfma_f32_16x16x32_f16(z.v, w4f, acc_z, 0, 0, 0);
                }

                // prefetch next tile's B
                {
                    const h16x4* nbp = feat + (size_t)(((unsigned)nrc) >> 16) * 16 + v0;
#pragma unroll
                    for (int k = 0; k < 8; ++k) Bt[k] = nbp[k];
                }

                // wave-local segmented epilogue
                int prevR = __shfl(myR, (lane + 63) & 63);
                int flag = (m == 0) || (myR != prevR);
                unsigned long long bal = __ballot(flag != 0);
                unsigned mask16 = (unsigned)(bal & 0xFFFFull);

                int nseg = __popc(mask16);
                unsigned rem = mask16;
                for (int s = 0; s < nseg; ++s) {
                    int lo = __ffs(rem) - 1;
                    rem &= rem - 1;
                    int hi = rem ? (__ffs(rem) - 1) : 16;
                    float ps = 0.f, px = 0.f, py = 0.f, pz = 0.f;
#pragma unroll
                    for (int r = 0; r < 4; ++r) {
                        int ei = q * 4 + r;
                        bool in = (ei >= lo) && (ei < hi);
                        ps += in ? acc_s[r] : 0.f;
                        px += in ? acc_x[r] : 0.f;
                        py += in ? acc_y[r] : 0.f;
                        pz += in ? acc_z[r] : 0.f;
                    }
                    ps += __shfl_xor(ps, 16); ps += __shfl_xor(ps, 32);
                    px += __shfl_xor(px, 16); px += __shfl_xor(px, 32);
                    py += __shfl_xor(py, 16); py += __shfl_xor(py, 32);
                    pz += __shfl_xor(pz, 16); pz += __shfl_xor(pz, 32);
                    int node = __shfl(myR, lo);
                    float val = (q == 0) ? ps : (q == 1) ? px : (q == 2) ? py : pz;
                    atomicAdd(acc + (size_t)node * 64 + m * 4 + q, val);
                }

                rc = nrc;
            }
        }
        gbar(barIdx++);   // edge phase l complete

        if (l < 2) {
            // -------- gate phase: acc -> fp16 (xALPHA), rezero acc --------
            float4* accv = (float4*)acc;
            h16x4* fo = (h16x4*)foutp;
            for (int i = tid; i < N_NODES * 16; i += nthreads) {
                float4 f = accv[i];
                float g = ALPHA / (1.f + __expf(-f.x));
                h16x4 o;
                o.x = (_Float16)(f.x * g);
                o.y = (_Float16)(f.y * g);
                o.z = (_Float16)(f.z * g);
                o.w = (_Float16)(f.w * g);
                fo[i] = o;
                accv[i] = make_float4(0.f, 0.f, 0.f, 0.f);
            }
            // ping-pong
            const _Float16* tmp = finp; finp = foutp; foutp = (_Float16*)tmp;
            gbar(barIdx++);   // gate l complete
        } else {
            // -------- readout phase --------
            float* bins = (float*)smraw;   // edge phase done; LDS reusable
            if (t < N_GRAPHS) bins[t] = 0.f;
            __syncthreads();
            for (int n = tid; n < N_NODES; n += nthreads) {
                const float4* f = (const float4*)acc + (size_t)n * 16;
                float a = 0.f;
#pragma unroll
                for (int w = 0; w < 16; ++w) {
                    float s = f[w].x;
                    float silu = s / (1.f + __expf(-s));
                    a += silu * w_out[w];
                }
                atomicAdd(&bins[batch_idx[n]], a * INV_LIN_OUT);
            }
            __syncthreads();
            if (t < N_GRAPHS) atomicAdd(&energy[t], bins[t]);
        }
    }
}

extern "C" void kernel_launch(void* const* d_in, const int* in_sizes, int n_in,
                              void* d_out, int out_size, void* d_ws, size_t ws_size,
                              hipStream_t stream) {
    const float* x         = (const float*)d_in[0];
    const int*   row       = (const int*)d_in[1];
    const int*   col       = (const int*)d_in[2];
    const int*   batch_idx = (const int*)d_in[3];
    const float* w_in0     = (const float*)d_in[4];
    const float* w_in1     = (const float*)d_in[5];
    const float* tp_w      = (const float*)d_in[6];   // [3][5][16][16][16]
    const float* w_out0    = (const float*)d_in[7];
    float* energy = (float*)d_out;

    // workspace layout (28.1 MB total)
    float*    acc   = (float*)d_ws;                        // [N][64] f32 accum
    _Float16* featA = (_Float16*)(acc + (size_t)N_NODES * 64);   // [N][64] f16
    _Float16* featB = featA + (size_t)N_NODES * 64;              // [N][64] f16
    _Float16* wh    = featB + (size_t)N_NODES * 64;              // [3][20480] f16
    int* sortedRC = (int*)(wh + 3 * 20480);                // [E] packed (row | col<<16)
    int* counts  = (int*)featB;   // transient sort scratch (dead until gate0)

    // grid = exact measured residency (once; pure driver query, no stream ops),
    // rounded to a multiple of 64 (barrier group math). Deadlock-free by
    // construction: barrier target is gridDim.x.
    static int megaGrid = 0;
    if (megaGrid == 0) {
        int nb = 0;
        hipError_t err = hipOccupancyMaxActiveBlocksPerMultiprocessor(
            &nb, mega_kernel, 256, 0);
        if (err != hipSuccess || nb < 1) nb = 4;   // (256,4) bound guarantees 4
        if (nb > 8) nb = 8;                         // 32-wave/CU cap
        megaGrid = (nb * 256) & ~63;                // 256 CUs; multiple of 64
        if (megaGrid < 256) megaGrid = 256;         // >= NPART for scan phases
    }

    // dispatch 1: proj -> featA (fp16), swizzle -> wh, zero counts/energy/acc/bars
    init_kernel<<<(3 * 20480 + 255) / 256, 256, 0, stream>>>(
        x, w_in0, w_in1, tp_w, (h16x4*)featA, wh, counts, energy, (float4*)acc);

    // dispatch 2: everything else, hierarchical-barrier separated
    mega_kernel<<<megaGrid, 256, 0, stream>>>(
        row, col, batch_idx, w_out0, wh, acc, featA, featB, sortedRC, energy);
}

// Round 9
// 488.112 us; speedup vs baseline: 9.8085x; 1.5328x over previous
//
#include <hip/hip_runtime.h>

#define N_NODES 50000
#define N_EDGES 600000
#define N_GRAPHS 64
#define N_TILES (N_EDGES / 16)   // 37500 wave-tiles
#define EDGE_GRID 2048           // R4-proven edge grid

#define SCAN_T 1024
#define SCAN_C 49                // ceil(50000/1024)

// constants
#define INV_LIN_IN  0.35355339059327373f   // 1/sqrt(8)
#define INV_LIN_OUT 0.25f                  // 1/sqrt(16)
#define C_INV_S3    0.5773502691896258f    // 1/sqrt(3)
#define C_INV_S2    0.7071067811865476f    // 1/sqrt(2)
#define C_NORM_S    0.04419417382415922f   // 1/sqrt(512)
#define C_NORM_V    0.036084391824351615f  // 1/sqrt(768)

// fp16 overflow guard: features entering layers 1,2 are scaled by ALPHA after
// the gate; the inverse (1/ALPHA^2 = 1024) is folded into those layers' weights.
// TP is bilinear so this is exact. Keeps layer-3 fp16 products ~56 max vs 65504.
#define ALPHA      0.03125f                // 1/32
#define W_UNSCALE  1024.0f                 // 1/ALPHA^2

typedef __attribute__((ext_vector_type(8))) _Float16 h16x8;
typedef __attribute__((ext_vector_type(4))) _Float16 h16x4;
typedef __attribute__((ext_vector_type(2))) _Float16 h16x2;
typedef __attribute__((ext_vector_type(4))) float f32x4;

// ==================== sort edges by destination (row); pack (row,col) in one int ====
__global__ void hist_kernel(const int* __restrict__ row, int* __restrict__ counts) {
    int e = blockIdx.x * 256 + threadIdx.x;
    if (e < N_EDGES) atomicAdd(&counts[row[e]], 1);
}

// single-block exclusive scan of 50000 counts -> cursor (replaces the two-kernel
// scan: no inter-block dependency, so one dispatch instead of two).
__global__ __launch_bounds__(SCAN_T)
void scan_one_kernel(const int* __restrict__ counts, int* __restrict__ cursor) {
    __shared__ int sm[SCAN_T];
    int t = threadIdx.x;
    int base = t * SCAN_C;
    int local[SCAN_C];
    int sum = 0;
#pragma unroll
    for (int k = 0; k < SCAN_C; ++k) {
        int i = base + k;
        int v = (i < N_NODES) ? counts[i] : 0;
        local[k] = sum;      // exclusive within this thread's chunk
        sum += v;
    }
    sm[t] = sum;
    __syncthreads();
    for (int s = 1; s < SCAN_T; s <<= 1) {   // inclusive scan of thread sums
        int add = (t >= s) ? sm[t - s] : 0;
        __syncthreads();
        sm[t] += add;
        __syncthreads();
    }
    int tbase = (t > 0) ? sm[t - 1] : 0;
#pragma unroll
    for (int k = 0; k < SCAN_C; ++k) {
        int i = base + k;
        if (i < N_NODES) cursor[i] = tbase + local[k];
    }
}

__global__ void scatter_kernel(const int* __restrict__ row, const int* __restrict__ col,
                               int* __restrict__ cursor, int* __restrict__ sortedRC) {
    int e = blockIdx.x * 256 + threadIdx.x;
    if (e < N_EDGES) {
        int n = row[e];
        int pos = atomicAdd(&cursor[n], 1);
        sortedRC[pos] = n | (col[e] << 16);   // node ids < 50000 < 65536
    }
}

// -------------------- fused init: proj (fp16 out) + weight swizzle (fp16) +
// counts-zero + energy-zero + acc-zero
__global__ void init_kernel(const float* __restrict__ x,
                            const float* __restrict__ w_in0,
                            const float* __restrict__ w_in1,
                            const float* __restrict__ tp_w,
                            h16x4* __restrict__ featH,
                            _Float16* __restrict__ wh,
                            int* __restrict__ counts,
                            float* __restrict__ energy,
                            float4* __restrict__ acc) {
    int gid = blockIdx.x * 256 + threadIdx.x;

    if (gid < 64) energy[gid] = 0.f;
    if (gid < N_NODES) counts[gid] = 0;

    // zero the f32 accumulator: 800k float4 over 61440 threads (grid-stride)
    for (int idx = gid; idx < N_NODES * 16; idx += 61440)
        acc[idx] = make_float4(0.f, 0.f, 0.f, 0.f);

    if (gid < 3 * 20480) {   // weight swizzle -> fp16 (one-time cost)
        int i = gid;
        int j    = i & 7;
        int t1   = i >> 3;
        int lane = t1 & 63;
        int t2   = t1 >> 6;
        int c    = t2 & 7;
        int t3   = t2 >> 3;
        int slot = t3 % 5;
        int l    = t3 / 5;
        int p = (slot == 0) ? 1 : (slot == 1) ? 2 : (slot == 2) ? 4 : (slot == 3) ? 0 : 3;
        int kk = c * 32 + (lane >> 4) * 8 + j;
        int u = kk >> 4, v = kk & 15, n = lane & 15;
        float scale;
        if      (p == 0) scale = C_NORM_S;
        else if (p == 3) scale = C_INV_S3 * C_NORM_S;
        else if (p == 4) scale = C_INV_S2 * C_NORM_V;
        else             scale = C_NORM_V;   // p==1, p==2
        if (l > 0) scale *= W_UNSCALE;       // undo ALPHA^2 feature pre-scale
        float val = tp_w[(size_t)(l * 5 + p) * 4096 + u * 256 + v * 16 + n] * scale;
        wh[i] = (_Float16)val;
    }

    if (gid < N_NODES) {     // input projection -> fp16 features (layer-0: unscaled)
        const float* xp = x + (size_t)gid * 32;
        float xs[8], xvx[8], xvy[8], xvz[8];
#pragma unroll
        for (int u = 0; u < 8; ++u) xs[u] = xp[u];
#pragma unroll
        for (int u = 0; u < 8; ++u) {
            xvx[u] = xp[8 + 3 * u + 0];
            xvy[u] = xp[8 + 3 * u + 1];
            xvz[u] = xp[8 + 3 * u + 2];
        }
#pragma unroll
        for (int w = 0; w < 16; ++w) {
            float s = 0.f, vx = 0.f, vy = 0.f, vz = 0.f;
#pragma unroll
            for (int u = 0; u < 8; ++u) {
                float a0 = w_in0[u * 16 + w];
                float a1 = w_in1[u * 16 + w];
                s  += xs[u]  * a0;
                vx += xvx[u] * a1;
                vy += xvy[u] * a1;
                vz += xvz[u] * a1;
            }
            h16x4 o;
            o.x = (_Float16)(s  * INV_LIN_IN);
            o.y = (_Float16)(vx * INV_LIN_IN);
            o.z = (_Float16)(vy * INV_LIN_IN);
            o.w = (_Float16)(vz * INV_LIN_IN);
            featH[(size_t)gid * 16 + w] = o;
        }
    }
}

// -------------------- edge tensor product (fp16): R4-proven. Persistent waves,
// W1/W2 in LDS (16KB), W4/W0/W3 from global (L1-hot); z-formation fully in
// packed v_pk_*_f16; unroll 4. launch_bounds(256,4): no hard reg cap (R3/R5
// lesson: forcing <=64/84 VGPR spills the MFMA loop to scratch).
__global__ __launch_bounds__(256, 4)
void edge_tp_kernel(const h16x4* __restrict__ feat,
                    float* __restrict__ out,          // [N][16][4] f32 accum
                    const int* __restrict__ sortedRC,
                    const _Float16* __restrict__ wh) {
    __shared__ h16x8 sW[1024];   // 16 KB: paths {1,2}

    const int t = threadIdx.x;
    {
        const int4* src = (const int4*)wh;
        int4* dst = (int4*)sW;
#pragma unroll
        for (int i = 0; i < 4; ++i) dst[t + 256 * i] = src[t + 256 * i];
    }
    __syncthreads();   // the only barrier

    const int lane = t & 63;
    const int wave = t >> 6;
    const int q = lane >> 4;        // quad 0..3
    const int m = lane & 15;        // edge-in-tile / w column
    const int v0 = (q & 1) * 8;

    const h16x8* gw = ((const h16x8*)wh) + 1024;   // paths {4,0,3} in global

    const int gw_id = blockIdx.x * 4 + wave;
    const int nw = gridDim.x * 4;
    int tile = (int)(((long long)gw_id * N_TILES) / nw);
    const int tileEnd = (int)(((long long)(gw_id + 1) * N_TILES) / nw);
    if (tile >= tileEnd) return;

    int rc = sortedRC[tile * 16 + m];
    h16x4 Bt[8];
    {
        const h16x4* bp = feat + (size_t)(((unsigned)rc) >> 16) * 16 + v0;
#pragma unroll
        for (int k = 0; k < 8; ++k) Bt[k] = bp[k];
    }

    for (; tile < tileEnd; ++tile) {
        const int myR = rc & 0xFFFF;
        const int nt = tile + 1;
        const int nrc = (nt < tileEnd) ? sortedRC[nt * 16 + m] : rc;

        // transpose gathered B into packed-f16 v-pairs (Bt dies here)
        h16x2 Bs[4], Bx[4], By[4], Bz[4];
#pragma unroll
        for (int k = 0; k < 4; ++k) {
            Bs[k].x = Bt[2 * k].x; Bs[k].y = Bt[2 * k + 1].x;
            Bx[k].x = Bt[2 * k].y; Bx[k].y = Bt[2 * k + 1].y;
            By[k].x = Bt[2 * k].z; By[k].y = Bt[2 * k + 1].z;
            Bz[k].x = Bt[2 * k].w; Bz[k].y = Bt[2 * k + 1].w;
        }

        f32x4 acc_s = {0.f, 0.f, 0.f, 0.f};
        f32x4 acc_x = {0.f, 0.f, 0.f, 0.f};
        f32x4 acc_y = {0.f, 0.f, 0.f, 0.f};
        f32x4 acc_z = {0.f, 0.f, 0.f, 0.f};

        const h16x4* ap = feat + (size_t)myR * 16;

#pragma unroll 4
        for (int c = 0; c < 8; ++c) {
            // global weight loads first (longest latency)
            h16x8 w4f = gw[(0 * 8 + c) * 64 + lane];   // path 4 (cross)
            h16x8 w0f = gw[(1 * 8 + c) * 64 + lane];   // path 0 (ss)
            h16x8 w3f = gw[(2 * 8 + c) * 64 + lane];   // path 3 (dot)
            h16x8 w1f = sW[(0 * 8 + c) * 64 + lane];
            h16x8 w2f = sW[(1 * 8 + c) * 64 + lane];

            h16x4 A = ap[2 * c + (q >> 1)];   // L1-hot (sorted rows)
            h16x2 s2; s2.x = A.x; s2.y = A.x;
            h16x2 x2; x2.x = A.y; x2.y = A.y;
            h16x2 y2; y2.x = A.z; y2.y = A.z;
            h16x2 z2; z2.x = A.w; z2.y = A.w;

            union { h16x8 v; h16x2 h[4]; } z;

            // ss = s1*s2 -> W0 (acc_s)
#pragma unroll
            for (int k = 0; k < 4; ++k) z.h[k] = s2 * Bs[k];
            acc_s = __builtin_amdgcn_mfma_f32_16x16x32_f16(z.v, w0f, acc_s, 0, 0, 0);

            // dot(v1,v2) -> W3 (acc_s)
#pragma unroll
            for (int k = 0; k < 4; ++k)
                z.h[k] = x2 * Bx[k] + y2 * By[k] + z2 * Bz[k];
            acc_s = __builtin_amdgcn_mfma_f32_16x16x32_f16(z.v, w3f, acc_s, 0, 0, 0);

            // s1*v2x -> W1 (acc_x)
#pragma unroll
            for (int k = 0; k < 4; ++k) z.h[k] = s2 * Bx[k];
            acc_x = __builtin_amdgcn_mfma_f32_16x16x32_f16(z.v, w1f, acc_x, 0, 0, 0);
            // v1x*s2 -> W2 (acc_x)
#pragma unroll
            for (int k = 0; k < 4; ++k) z.h[k] = x2 * Bs[k];
            acc_x = __builtin_amdgcn_mfma_f32_16x16x32_f16(z.v, w2f, acc_x, 0, 0, 0);
            // cross_x = v1y*v2z - v1z*v2y -> W4 (acc_x)
#pragma unroll
            for (int k = 0; k < 4; ++k) z.h[k] = y2 * Bz[k] - z2 * By[k];
            acc_x = __builtin_amdgcn_mfma_f32_16x16x32_f16(z.v, w4f, acc_x, 0, 0, 0);

            // s1*v2y -> W1 (acc_y)
#pragma unroll
            for (int k = 0; k < 4; ++k) z.h[k] = s2 * By[k];
            acc_y = __builtin_amdgcn_mfma_f32_16x16x32_f16(z.v, w1f, acc_y, 0, 0, 0);
            // v1y*s2 -> W2 (acc_y)
#pragma unroll
            for (int k = 0; k < 4; ++k) z.h[k] = y2 * Bs[k];
            acc_y = __builtin_amdgcn_mfma_f32_16x16x32_f16(z.v, w2f, acc_y, 0, 0, 0);
            // cross_y = v1z*v2x - v1x*v2z -> W4 (acc_y)
#pragma unroll
            for (int k = 0; k < 4; ++k) z.h[k] = z2 * Bx[k] - x2 * Bz[k];
            acc_y = __builtin_amdgcn_mfma_f32_16x16x32_f16(z.v, w4f, acc_y, 0, 0, 0);

            // s1*v2z -> W1 (acc_z)
#pragma unroll
            for (int k = 0; k < 4; ++k) z.h[k] = s2 * Bz[k];
            acc_z = __builtin_amdgcn_mfma_f32_16x16x32_f16(z.v, w1f, acc_z, 0, 0, 0);
            // v1z*s2 -> W2 (acc_z)
#pragma unroll
            for (int k = 0; k < 4; ++k) z.h[k] = z2 * Bs[k];
            acc_z = __builtin_amdgcn_mfma_f32_16x16x32_f16(z.v, w2f, acc_z, 0, 0, 0);
            // cross_z = v1x*v2y - v1y*v2x -> W4 (acc_z)
#pragma unroll
            for (int k = 0; k < 4; ++k) z.h[k] = x2 * By[k] - y2 * Bx[k];
            acc_z = __builtin_amdgcn_mfma_f32_16x16x32_f16(z.v, w4f, acc_z, 0, 0, 0);
        }

        // prefetch next tile's B into Bt AFTER the chunk loop
        {
            const h16x4* nbp = feat + (size_t)(((unsigned)nrc) >> 16) * 16 + v0;
#pragma unroll
            for (int k = 0; k < 8; ++k) Bt[k] = nbp[k];
        }

        // ---------- wave-local segmented epilogue (shuffle reduction) ----------
        int prevR = __shfl(myR, (lane + 63) & 63);
        int flag = (m == 0) || (myR != prevR);
        unsigned long long bal = __ballot(flag != 0);
        unsigned mask16 = (unsigned)(bal & 0xFFFFull);   // identical across quads

        int nseg = __popc(mask16);
        unsigned rem = mask16;
        for (int s = 0; s < nseg; ++s) {
            int lo = __ffs(rem) - 1;
            rem &= rem - 1;
            int hi = rem ? (__ffs(rem) - 1) : 16;
            float ps = 0.f, px = 0.f, py = 0.f, pz = 0.f;
#pragma unroll
            for (int r = 0; r < 4; ++r) {
                int ei = q * 4 + r;
                bool in = (ei >= lo) && (ei < hi);
                ps += in ? acc_s[r] : 0.f;
                px += in ? acc_x[r] : 0.f;
                py += in ? acc_y[r] : 0.f;
                pz += in ? acc_z[r] : 0.f;
            }
            ps += __shfl_xor(ps, 16); ps += __shfl_xor(ps, 32);
            px += __shfl_xor(px, 16); px += __shfl_xor(px, 32);
            py += __shfl_xor(py, 16); py += __shfl_xor(py, 32);
            pz += __shfl_xor(pz, 16); pz += __shfl_xor(pz, 32);
            int node = __shfl(myR, lo);
            float val = (q == 0) ? ps : (q == 1) ? px : (q == 2) ? py : pz;
            atomicAdd(out + (size_t)node * 64 + m * 4 + q, val);
        }

        rc = nrc;
    }
}

// -------------------- gate acc -> fp16 features (pre-scaled by ALPHA) + zero acc
__global__ void gate_half_kernel(float4* __restrict__ acc,
                                 h16x4* __restrict__ featH) {
    int i = blockIdx.x * 256 + threadIdx.x;   // (n*16 + w)
    if (i >= N_NODES * 16) return;
    float4 f = acc[i];
    float g = ALPHA / (1.f + __expf(-f.x));   // sigmoid * feature pre-scale
    h16x4 o;
    o.x = (_Float16)(f.x * g);
    o.y = (_Float16)(f.y * g);
    o.z = (_Float16)(f.z * g);
    o.w = (_Float16)(f.w * g);
    featH[i] = o;
    acc[i] = make_float4(0.f, 0.f, 0.f, 0.f);
}

// -------------------- final gate + readout fused (reads f32 acc)
__global__ void gate_readout_kernel(const float4* __restrict__ feat,
                                    const int* __restrict__ batch_idx,
                                    const float* __restrict__ w_out,
                                    float* __restrict__ energy) {
    __shared__ float bins[N_GRAPHS];
    int t = threadIdx.x;
    if (t < N_GRAPHS) bins[t] = 0.f;
    __syncthreads();
    int n = blockIdx.x * 256 + t;
    if (n < N_NODES) {
        const float4* f = feat + (size_t)n * 16;
        float acc = 0.f;
#pragma unroll
        for (int w = 0; w < 16; ++w) {
            float s = f[w].x;
            float silu = s / (1.f + __expf(-s));
            acc += silu * w_out[w];
        }
        atomicAdd(&bins[batch_idx[n]], acc * INV_LIN_OUT);
    }
    __syncthreads();
    if (t < N_GRAPHS) atomicAdd(&energy[t], bins[t]);
}

extern "C" void kernel_launch(void* const* d_in, const int* in_sizes, int n_in,
                              void* d_out, int out_size, void* d_ws, size_t ws_size,
                              hipStream_t stream) {
    const float* x         = (const float*)d_in[0];
    const int*   row       = (const int*)d_in[1];
    const int*   col       = (const int*)d_in[2];
    const int*   batch_idx = (const int*)d_in[3];
    const float* w_in0     = (const float*)d_in[4];
    const float* w_in1     = (const float*)d_in[5];
    const float* tp_w      = (const float*)d_in[6];   // [3][5][16][16][16]
    const float* w_out0    = (const float*)d_in[7];
    float* energy = (float*)d_out;

    // workspace layout (28.1 MB total)
    float*    acc   = (float*)d_ws;                        // [N][64] f32 accum
    _Float16* featA = (_Float16*)(acc + (size_t)N_NODES * 64);   // [N][64] f16
    _Float16* featB = featA + (size_t)N_NODES * 64;              // [N][64] f16
    _Float16* wh    = featB + (size_t)N_NODES * 64;              // [3][20480] f16
    int* sortedRC = (int*)(wh + 3 * 20480);                // [E] packed (row | col<<16)
    // transient sort scratch aliased into featB (dead until layer-1 gate writes it)
    int* counts  = (int*)featB;
    int* cursor  = counts + N_NODES;

    // fused init: proj -> featA (fp16), swizzle -> wh, zero counts/energy/acc
    init_kernel<<<(3 * 20480 + 255) / 256, 256, 0, stream>>>(
        x, w_in0, w_in1, tp_w, (h16x4*)featA, wh, counts, energy, (float4*)acc);

    // build destination-sorted edge list (3 dispatches: hist, 1-block scan, scatter)
    hist_kernel<<<(N_EDGES + 255) / 256, 256, 0, stream>>>(row, counts);
    scan_one_kernel<<<1, SCAN_T, 0, stream>>>(counts, cursor);
    scatter_kernel<<<(N_EDGES + 255) / 256, 256, 0, stream>>>(row, col, cursor, sortedRC);

    _Float16* fin = featA;
    _Float16* fnext = featB;
    for (int l = 0; l < 3; ++l) {
        edge_tp_kernel<<<EDGE_GRID, 256, 0, stream>>>(
            (const h16x4*)fin, acc, sortedRC, wh + (size_t)l * 20480);
        if (l < 2) {
            // gate acc -> fp16 features (x ALPHA) for next layer; re-zero acc
            gate_half_kernel<<<(N_NODES * 16 + 255) / 256, 256, 0, stream>>>(
                (float4*)acc, (h16x4*)fnext);
            _Float16* tmp = fin; fin = fnext; fnext = tmp;
        } else {
            gate_readout_kernel<<<(N_NODES + 255) / 256, 256, 0, stream>>>(
                (const float4*)acc, batch_idx, w_out0, energy);
        }
    }
}